// Round 1
// baseline (294.083 us; speedup 1.0000x reference)
//
#include <hip/hip_runtime.h>
#include <cstdint>

typedef unsigned short u16;
typedef __bf16 bf16x8 __attribute__((ext_vector_type(8)));
typedef float f32x4 __attribute__((ext_vector_type(4)));

#define NEG_INF (-__builtin_inff())

__device__ __forceinline__ u16 f2bf(float f) {
  unsigned u = __builtin_bit_cast(unsigned, f);
  u += 0x7FFFu + ((u >> 16) & 1u);
  return (u16)(u >> 16);
}
__device__ __forceinline__ u16 bfbits(__bf16 x) { return __builtin_bit_cast(u16, x); }

// global->LDS async copy, 16B per lane. LDS dest is wave-uniform base + lane*16.
__device__ __forceinline__ void async16(u16* dst, const u16* src) {
  __builtin_amdgcn_global_load_lds(
      (__attribute__((address_space(1))) void*)(u16*)src,
      (__attribute__((address_space(3))) void*)dst, 16, 0, 0);
}

// ---------------- fp32 -> bf16 convert (8 elems/thread) ----------------
__global__ __launch_bounds__(256) void k_cvt(const float4* __restrict__ in,
                                             uint4* __restrict__ out, int n8) {
  int i = blockIdx.x * 256 + threadIdx.x;
  if (i >= n8) return;
  float4 a = in[2 * i], b = in[2 * i + 1];
  uint4 r;
  r.x = (unsigned)f2bf(a.x) | ((unsigned)f2bf(a.y) << 16);
  r.y = (unsigned)f2bf(a.z) | ((unsigned)f2bf(a.w) << 16);
  r.z = (unsigned)f2bf(b.x) | ((unsigned)f2bf(b.y) << 16);
  r.w = (unsigned)f2bf(b.z) | ((unsigned)f2bf(b.w) << 16);
  out[i] = r;
}

// ------------- batched transpose+convert: in (B,R,C) f32 -> out (B,C,R) bf16 -------------
__global__ __launch_bounds__(256) void k_transpose(const float* __restrict__ in,
                                                   u16* __restrict__ out, int R, int C) {
  __shared__ float t[32][65];
  int b = blockIdx.z;
  int r0 = blockIdx.y * 32, c0 = blockIdx.x * 64;
  const float* ip = in + (size_t)b * R * C;
  u16* op = out + (size_t)b * R * C;
  int tx = threadIdx.x & 63, ty = threadIdx.x >> 6;
#pragma unroll
  for (int i = 0; i < 32; i += 4) {
    int r = r0 + ty + i, c = c0 + tx;
    t[ty + i][tx] = (r < R && c < C) ? ip[(size_t)r * C + c] : 0.f;
  }
  __syncthreads();
  int cx = threadIdx.x & 31, cy = threadIdx.x >> 5;
#pragma unroll
  for (int j = 0; j < 64; j += 8) {
    int oc = c0 + cy + j, orr = r0 + cx;
    if (oc < C && orr < R) op[(size_t)oc * R + orr] = f2bf(t[cx][cy + j]);
  }
}

__global__ __launch_bounds__(256) void k_pack_bias(const float* __restrict__ bq,
                                                   const float* __restrict__ bk,
                                                   const float* __restrict__ bv,
                                                   float* __restrict__ bpk) {
  int i = blockIdx.x * 256 + threadIdx.x;
  if (i < 1536) {
    int m = i >> 9, r = i & 511;
    const float* B = (m == 0) ? bq : (m == 1) ? bk : bv;
    bpk[i] = B[r];
  }
}

// ---------------- bf16 MFMA GEMM: C(M,N) = A(M,K) * BT(N,K)^T + bias ----------------
// EPI: 0 = bf16 store, 1 = bf16 store + relu, 2 = f32 store
template <int EPI>
__global__ __launch_bounds__(256) void k_gemm(const u16* __restrict__ A,
                                              const u16* __restrict__ BT,
                                              const float* __restrict__ bias,
                                              void* __restrict__ Cout,
                                              int M, int N, int Kd) {
  __shared__ __align__(16) u16 lds[16384];  // A tile [128][64] + B tile [128][64], XOR-swizzled
  const int tid = threadIdx.x, wid = tid >> 6, lane = tid & 63;
  const int lr = lane & 15, lg = lane >> 4;
  const int wr = wid >> 1, wc = wid & 1;
  const int tm = blockIdx.x * 128, tn = blockIdx.y * 128;
  const char* lp = (const char*)lds;

  f32x4 acc[4][4] = {};

  const int srow = lane >> 3;            // row within 8-row staging region
  const int kb = (lane & 7) ^ srow;      // pre-swizzled source chunk

  for (int kt = 0; kt < Kd; kt += 64) {
#pragma unroll
    for (int it = 0; it < 4; ++it) {
      int rid = wid * 4 + it;
      int row = rid * 8 + srow;
      async16(&lds[rid * 512], A + (size_t)(tm + row) * Kd + kt + kb * 8);
      async16(&lds[8192 + rid * 512], BT + (size_t)(tn + row) * Kd + kt + kb * 8);
    }
    __syncthreads();
#pragma unroll
    for (int ks = 0; ks < 2; ++ks) {
      const int kbyte = ks * 64 + lg * 16;
      bf16x8 af[4], bf[4];
#pragma unroll
      for (int mi = 0; mi < 4; ++mi) {
        int row = wr * 64 + mi * 16 + lr;
        af[mi] = *(const bf16x8*)(lp + row * 128 + (kbyte ^ ((row & 7) << 4)));
      }
#pragma unroll
      for (int nj = 0; nj < 4; ++nj) {
        int row = wc * 64 + nj * 16 + lr;
        bf[nj] = *(const bf16x8*)(lp + 16384 + row * 128 + (kbyte ^ ((row & 7) << 4)));
      }
#pragma unroll
      for (int mi = 0; mi < 4; ++mi)
#pragma unroll
        for (int nj = 0; nj < 4; ++nj)
          acc[mi][nj] = __builtin_amdgcn_mfma_f32_16x16x32_bf16(af[mi], bf[nj], acc[mi][nj], 0, 0, 0);
    }
    __syncthreads();
  }

#pragma unroll
  for (int mi = 0; mi < 4; ++mi)
#pragma unroll
    for (int nj = 0; nj < 4; ++nj) {
      int col = tn + wc * 64 + nj * 16 + lr;
      float bv = bias[col];
#pragma unroll
      for (int r = 0; r < 4; ++r) {
        int row = tm + wr * 64 + mi * 16 + lg * 4 + r;
        float v = acc[mi][nj][r] + bv;
        if (EPI == 1) v = v > 0.f ? v : 0.f;
        if (EPI == 2)
          ((float*)Cout)[(size_t)row * N + col] = v;
        else
          ((u16*)Cout)[(size_t)row * N + col] = f2bf(v);
      }
    }
}

// ---------------- causal flash attention ----------------
// QKV: (8192, 1536) bf16, cols [q | k | v] each h*64+e. att out: (8192, 512) bf16.
__global__ __launch_bounds__(256) void k_attn(const u16* __restrict__ QKV,
                                              u16* __restrict__ att) {
  __shared__ __align__(16) u16 lds[16384];  // K [64][64] swz | VT [64][64] swz | P 4x[32][64] swz
  const int qt = blockIdx.x, nh = blockIdx.y;
  const int n = nh >> 3, h = nh & 7;
  const int tid = threadIdx.x, wid = tid >> 6, lane = tid & 63;
  const int lr = lane & 15, lg = lane >> 4;
  const int q0 = qt * 128, wq = wid * 32;
  const char* lp = (const char*)lds;

  const u16* Qp = QKV + (size_t)(n * 2048) * 1536 + h * 64;
  const u16* Kp = Qp + 512;
  const u16* Vp = Qp + 1024;

  bf16x8 qf[2][2];
#pragma unroll
  for (int mi = 0; mi < 2; ++mi)
#pragma unroll
    for (int ds = 0; ds < 2; ++ds) {
      int row = q0 + wq + mi * 16 + lr;
      qf[mi][ds] = *(const bf16x8*)(Qp + (size_t)row * 1536 + ds * 32 + lg * 8);
    }

  f32x4 o[2][4] = {};
  float mstat[2][4], lstat[2][4];
#pragma unroll
  for (int mi = 0; mi < 2; ++mi)
#pragma unroll
    for (int r = 0; r < 4; ++r) { mstat[mi][r] = NEG_INF; lstat[mi][r] = 0.f; }

  const int srow = lane >> 3;
  const int kb = (lane & 7) ^ srow;
  const int nt = 2 * qt + 2;
  for (int t = 0; t < nt; ++t) {
    const int kv0 = t * 64;
    __syncthreads();
    // stage K tile (swizzled via pre-swizzled global source)
#pragma unroll
    for (int it = 0; it < 2; ++it) {
      int rid = wid * 2 + it;
      int row = rid * 8 + srow;
      async16(&lds[rid * 512], Kp + (size_t)(kv0 + row) * 1536 + kb * 8);
    }
    // stage V^T (manual transpose, swizzled)
#pragma unroll
    for (int i = 0; i < 2; ++i) {
      int c = tid + i * 256;
      int kv = c & 63, dch = c >> 6;
      bf16x8 v = *(const bf16x8*)(Vp + (size_t)(kv0 + kv) * 1536 + dch * 8);
#pragma unroll
      for (int j = 0; j < 8; ++j) {
        int d = dch * 8 + j;
        int bo = (kv * 2) ^ ((d & 7) << 4);
        lds[4096 + d * 64 + (bo >> 1)] = bfbits(v[j]);
      }
    }
    __syncthreads();

    // S = Q K^T
    bf16x8 kf[4][2];
#pragma unroll
    for (int nj = 0; nj < 4; ++nj)
#pragma unroll
      for (int ks = 0; ks < 2; ++ks) {
        int row = nj * 16 + lr;
        int kbyte = ks * 64 + lg * 16;
        kf[nj][ks] = *(const bf16x8*)(lp + row * 128 + (kbyte ^ ((row & 7) << 4)));
      }
    f32x4 s[2][4] = {};
#pragma unroll
    for (int mi = 0; mi < 2; ++mi)
#pragma unroll
      for (int nj = 0; nj < 4; ++nj)
#pragma unroll
        for (int ks = 0; ks < 2; ++ks)
          s[mi][nj] = __builtin_amdgcn_mfma_f32_16x16x32_bf16(qf[mi][ks], kf[nj][ks], s[mi][nj], 0, 0, 0);

    // scale + causal mask
    const bool partial = (t >= 2 * qt);
#pragma unroll
    for (int mi = 0; mi < 2; ++mi)
#pragma unroll
      for (int nj = 0; nj < 4; ++nj)
#pragma unroll
        for (int r = 0; r < 4; ++r) {
          float v = s[mi][nj][r] * 0.125f;
          if (partial) {
            int qrow = q0 + wq + mi * 16 + lg * 4 + r;
            int kcol = kv0 + nj * 16 + lr;
            if (kcol > qrow) v = NEG_INF;
          }
          s[mi][nj][r] = v;
        }

    // online softmax (per q-row stats; rows live in 16-lane groups)
#pragma unroll
    for (int mi = 0; mi < 2; ++mi)
#pragma unroll
      for (int r = 0; r < 4; ++r) {
        float mx = fmaxf(fmaxf(s[mi][0][r], s[mi][1][r]), fmaxf(s[mi][2][r], s[mi][3][r]));
        mx = fmaxf(mx, __shfl_xor(mx, 1));
        mx = fmaxf(mx, __shfl_xor(mx, 2));
        mx = fmaxf(mx, __shfl_xor(mx, 4));
        mx = fmaxf(mx, __shfl_xor(mx, 8));
        float mold = mstat[mi][r];
        float mnew = fmaxf(mold, mx);
        mstat[mi][r] = mnew;
        float corr = __expf(mold - mnew);
        float psum = 0.f;
#pragma unroll
        for (int nj = 0; nj < 4; ++nj) {
          float p = __expf(s[mi][nj][r] - mnew);
          s[mi][nj][r] = p;
          psum += p;
        }
        psum += __shfl_xor(psum, 1);
        psum += __shfl_xor(psum, 2);
        psum += __shfl_xor(psum, 4);
        psum += __shfl_xor(psum, 8);
        lstat[mi][r] = lstat[mi][r] * corr + psum;
#pragma unroll
        for (int nd = 0; nd < 4; ++nd) o[mi][nd][r] *= corr;
      }

    // write P (wave-private region, swizzled) then PV
    const int wb = 8192 + wid * 2048;
#pragma unroll
    for (int mi = 0; mi < 2; ++mi)
#pragma unroll
      for (int nj = 0; nj < 4; ++nj)
#pragma unroll
        for (int r = 0; r < 4; ++r) {
          int prow = mi * 16 + lg * 4 + r;
          int pcol = nj * 16 + lr;
          int bo = (pcol * 2) ^ ((prow & 7) << 4);
          lds[wb + prow * 64 + (bo >> 1)] = f2bf(s[mi][nj][r]);
        }
#pragma unroll
    for (int ks = 0; ks < 2; ++ks) {
      const int kbyte = ks * 64 + lg * 16;
      bf16x8 pa[2], vf[4];
#pragma unroll
      for (int mi = 0; mi < 2; ++mi) {
        int prow = mi * 16 + lr;
        pa[mi] = *(const bf16x8*)(lp + wb * 2 + prow * 128 + (kbyte ^ ((prow & 7) << 4)));
      }
#pragma unroll
      for (int nd = 0; nd < 4; ++nd) {
        int vrow = nd * 16 + lr;
        vf[nd] = *(const bf16x8*)(lp + 8192 + vrow * 128 + (kbyte ^ ((vrow & 7) << 4)));
      }
#pragma unroll
      for (int mi = 0; mi < 2; ++mi)
#pragma unroll
        for (int nd = 0; nd < 4; ++nd)
          o[mi][nd] = __builtin_amdgcn_mfma_f32_16x16x32_bf16(pa[mi], vf[nd], o[mi][nd], 0, 0, 0);
    }
  }

#pragma unroll
  for (int mi = 0; mi < 2; ++mi)
#pragma unroll
    for (int nd = 0; nd < 4; ++nd)
#pragma unroll
      for (int r = 0; r < 4; ++r) {
        int row = q0 + wq + mi * 16 + lg * 4 + r;
        int col = nd * 16 + lr;
        float val = o[mi][nd][r] / lstat[mi][r];
        att[(size_t)(n * 2048 + row) * 512 + h * 64 + col] = f2bf(val);
      }
}

// ---------------- residual add + LayerNorm (D=512), optional bf16 copy ----------------
__global__ __launch_bounds__(256) void k_add_ln(const float* __restrict__ X,
                                                const float* __restrict__ Y,
                                                const float* __restrict__ gam,
                                                const float* __restrict__ bet,
                                                float* __restrict__ outf,
                                                u16* __restrict__ outb) {
  int row = blockIdx.x, t = threadIdx.x;
  const float* x = X + (size_t)row * 512;
  const float* y = Y + (size_t)row * 512;
  float v0 = x[t] + y[t];
  float v1 = x[t + 256] + y[t + 256];
  float s = v0 + v1, ss = v0 * v0 + v1 * v1;
#pragma unroll
  for (int m = 1; m < 64; m <<= 1) { s += __shfl_xor(s, m); ss += __shfl_xor(ss, m); }
  __shared__ float red[2][4];
  int wid = t >> 6;
  if ((t & 63) == 0) { red[0][wid] = s; red[1][wid] = ss; }
  __syncthreads();
  s = red[0][0] + red[0][1] + red[0][2] + red[0][3];
  ss = red[1][0] + red[1][1] + red[1][2] + red[1][3];
  float mean = s * (1.f / 512.f);
  float var = ss * (1.f / 512.f) - mean * mean;
  float rstd = rsqrtf(var + 1e-10f);
  float o0 = gam[t] * (v0 - mean) * rstd + bet[t];
  float o1 = gam[t + 256] * (v1 - mean) * rstd + bet[t + 256];
  float* of = outf + (size_t)row * 512;
  of[t] = o0;
  of[t + 256] = o1;
  if (outb) {
    u16* ob = outb + (size_t)row * 512;
    ob[t] = f2bf(o0);
    ob[t + 256] = f2bf(o1);
  }
}

extern "C" void kernel_launch(void* const* d_in, const int* in_sizes, int n_in,
                              void* d_out, int out_size, void* d_ws, size_t ws_size,
                              hipStream_t stream) {
  const float* x  = (const float*)d_in[0];
  const float* Wq = (const float*)d_in[1];
  const float* bq = (const float*)d_in[2];
  const float* Wk = (const float*)d_in[3];
  const float* bk = (const float*)d_in[4];
  const float* Wv = (const float*)d_in[5];
  const float* bv = (const float*)d_in[6];
  const float* Wo = (const float*)d_in[7];
  const float* bo = (const float*)d_in[8];
  const float* W1 = (const float*)d_in[9];
  const float* b1 = (const float*)d_in[10];
  const float* W2 = (const float*)d_in[11];
  const float* b2 = (const float*)d_in[12];
  const float* g1 = (const float*)d_in[13];
  const float* be1 = (const float*)d_in[14];
  const float* g2 = (const float*)d_in[15];
  const float* be2 = (const float*)d_in[16];
  // d_in[17] = mask: exactly causal, applied analytically.

  char* ws = (char*)d_ws;
  // region 0 [0,8M): xb -> att -> h1b (sequential lifetimes)
  u16* xb   = (u16*)(ws + 0);
  u16* attb = (u16*)(ws + 0);
  u16* h1b  = (u16*)(ws + 0);
  // region 1 [8M,~14.7M): bf16 transposed weights + packed bias (persistent)
  u16* WqkvT = (u16*)(ws + (size_t)(8u << 20));
  u16* WoT = WqkvT + 786432;
  u16* W1T = WoT + 262144;
  u16* W2T = W1T + 1048576;
  float* bqkv = (float*)(W2T + 1048576);
  // region 2 [16M,49.6M): QKV -> attproj -> ff1 (sequential lifetimes)
  u16* QKV = (u16*)(ws + (size_t)(16u << 20));
  float* attproj = (float*)(ws + (size_t)(16u << 20));
  u16* ff1 = (u16*)(ws + (size_t)(16u << 20));
  // region 3 [50M,66.8M): ffn2
  float* ffn2 = (float*)(ws + (size_t)(50u << 20));
  // h1 (fp32) parked in d_out, overwritten by final LN
  float* h1f = (float*)d_out;

  // 1) converts / transposes
  k_cvt<<<2048, 256, 0, stream>>>((const float4*)x, (uint4*)xb, 524288);
  k_transpose<<<dim3(1, 16, 8), 256, 0, stream>>>(Wq, WqkvT, 512, 64);
  k_transpose<<<dim3(1, 16, 8), 256, 0, stream>>>(Wk, WqkvT + 262144, 512, 64);
  k_transpose<<<dim3(1, 16, 8), 256, 0, stream>>>(Wv, WqkvT + 524288, 512, 64);
  k_transpose<<<dim3(8, 16, 1), 256, 0, stream>>>(Wo, WoT, 512, 512);
  k_transpose<<<dim3(32, 16, 1), 256, 0, stream>>>(W1, W1T, 512, 2048);
  k_transpose<<<dim3(8, 64, 1), 256, 0, stream>>>(W2, W2T, 2048, 512);
  k_pack_bias<<<6, 256, 0, stream>>>(bq, bk, bv, bqkv);

  // 2) QKV projection: (8192,512) @ (512,1536)
  k_gemm<0><<<dim3(64, 12), 256, 0, stream>>>(xb, WqkvT, bqkv, QKV, 8192, 1536, 512);
  // 3) causal attention
  k_attn<<<dim3(16, 32), 256, 0, stream>>>(QKV, attb);
  // 4) output projection (fp32 out)
  k_gemm<2><<<dim3(64, 4), 256, 0, stream>>>(attb, WoT, bo, attproj, 8192, 512, 512);
  // 5) h1 = LN(x + attproj)
  k_add_ln<<<8192, 256, 0, stream>>>(x, attproj, g1, be1, h1f, h1b);
  // 6) FFN
  k_gemm<1><<<dim3(64, 16), 256, 0, stream>>>(h1b, W1T, b1, ff1, 8192, 2048, 512);
  k_gemm<2><<<dim3(64, 4), 256, 0, stream>>>(ff1, W2T, b2, ffn2, 8192, 512, 2048);
  // 7) out = LN(h1 + ffn2)
  k_add_ln<<<8192, 256, 0, stream>>>(h1f, ffn2, g2, be2, (float*)d_out, nullptr);
}

// Round 2
// 234.977 us; speedup vs baseline: 1.2515x; 1.2515x over previous
//
#include <hip/hip_runtime.h>
#include <cstdint>

typedef unsigned short u16;
typedef __bf16 bf16x8 __attribute__((ext_vector_type(8)));
typedef float f32x4 __attribute__((ext_vector_type(4)));
struct __align__(8) U2 { unsigned x, y; };

#define NEG_INF (-__builtin_inff())

__device__ __forceinline__ u16 f2bf(float f) {
  unsigned u = __builtin_bit_cast(unsigned, f);
  u += 0x7FFFu + ((u >> 16) & 1u);
  return (u16)(u >> 16);
}
__device__ __forceinline__ u16 bfbits(__bf16 x) { return __builtin_bit_cast(u16, x); }

// global->LDS async copy, 16B per lane. LDS dest is wave-uniform base + lane*16.
__device__ __forceinline__ void async16(u16* dst, const u16* src) {
  __builtin_amdgcn_global_load_lds(
      (__attribute__((address_space(1))) void*)(u16*)src,
      (__attribute__((address_space(3))) void*)dst, 16, 0, 0);
}

// ---------------- fp32 -> bf16 convert (8 elems/thread) ----------------
__global__ __launch_bounds__(256) void k_cvt(const float4* __restrict__ in,
                                             uint4* __restrict__ out, int n8) {
  int i = blockIdx.x * 256 + threadIdx.x;
  if (i >= n8) return;
  float4 a = in[2 * i], b = in[2 * i + 1];
  uint4 r;
  r.x = (unsigned)f2bf(a.x) | ((unsigned)f2bf(a.y) << 16);
  r.y = (unsigned)f2bf(a.z) | ((unsigned)f2bf(a.w) << 16);
  r.z = (unsigned)f2bf(b.x) | ((unsigned)f2bf(b.y) << 16);
  r.w = (unsigned)f2bf(b.z) | ((unsigned)f2bf(b.w) << 16);
  out[i] = r;
}

// ------------- batched transpose+convert: in (B,R,C) f32 -> out (B,C,R) bf16 -------------
__global__ __launch_bounds__(256) void k_transpose(const float* __restrict__ in,
                                                   u16* __restrict__ out, int R, int C) {
  __shared__ float t[32][65];
  int b = blockIdx.z;
  int r0 = blockIdx.y * 32, c0 = blockIdx.x * 64;
  const float* ip = in + (size_t)b * R * C;
  u16* op = out + (size_t)b * R * C;
  int tx = threadIdx.x & 63, ty = threadIdx.x >> 6;
#pragma unroll
  for (int i = 0; i < 32; i += 4) {
    int r = r0 + ty + i, c = c0 + tx;
    t[ty + i][tx] = (r < R && c < C) ? ip[(size_t)r * C + c] : 0.f;
  }
  __syncthreads();
  int cx = threadIdx.x & 31, cy = threadIdx.x >> 5;
#pragma unroll
  for (int j = 0; j < 64; j += 8) {
    int oc = c0 + cy + j, orr = r0 + cx;
    if (oc < C && orr < R) op[(size_t)oc * R + orr] = f2bf(t[cx][cy + j]);
  }
}

__global__ __launch_bounds__(256) void k_pack_bias(const float* __restrict__ bq,
                                                   const float* __restrict__ bk,
                                                   const float* __restrict__ bv,
                                                   float* __restrict__ bpk) {
  int i = blockIdx.x * 256 + threadIdx.x;
  if (i < 1536) {
    int m = i >> 9, r = i & 511;
    const float* B = (m == 0) ? bq : (m == 1) ? bk : bv;
    bpk[i] = B[r];
  }
}

// ---------------- bf16 MFMA GEMM: C(M,N) = A(M,K) * BT(N,K)^T + bias ----------------
// EPI: 0 = bf16 store, 1 = bf16 store + relu, 2 = f32 store
template <int EPI>
__global__ __launch_bounds__(256) void k_gemm(const u16* __restrict__ A,
                                              const u16* __restrict__ BT,
                                              const float* __restrict__ bias,
                                              void* __restrict__ Cout,
                                              int M, int N, int Kd) {
  __shared__ __align__(16) u16 lds[16384];  // A tile [128][64] + B tile [128][64], XOR-swizzled
  const int tid = threadIdx.x, wid = tid >> 6, lane = tid & 63;
  const int lr = lane & 15, lg = lane >> 4;
  const int wr = wid >> 1, wc = wid & 1;
  const int tm = blockIdx.x * 128, tn = blockIdx.y * 128;
  const char* lp = (const char*)lds;

  f32x4 acc[4][4] = {};

  const int srow = lane >> 3;            // row within 8-row staging region
  const int kb = (lane & 7) ^ srow;      // pre-swizzled source chunk

  for (int kt = 0; kt < Kd; kt += 64) {
#pragma unroll
    for (int it = 0; it < 4; ++it) {
      int rid = wid * 4 + it;
      int row = rid * 8 + srow;
      async16(&lds[rid * 512], A + (size_t)(tm + row) * Kd + kt + kb * 8);
      async16(&lds[8192 + rid * 512], BT + (size_t)(tn + row) * Kd + kt + kb * 8);
    }
    __syncthreads();
#pragma unroll
    for (int ks = 0; ks < 2; ++ks) {
      const int kbyte = ks * 64 + lg * 16;
      bf16x8 af[4], bf[4];
#pragma unroll
      for (int mi = 0; mi < 4; ++mi) {
        int row = wr * 64 + mi * 16 + lr;
        af[mi] = *(const bf16x8*)(lp + row * 128 + (kbyte ^ ((row & 7) << 4)));
      }
#pragma unroll
      for (int nj = 0; nj < 4; ++nj) {
        int row = wc * 64 + nj * 16 + lr;
        bf[nj] = *(const bf16x8*)(lp + 16384 + row * 128 + (kbyte ^ ((row & 7) << 4)));
      }
#pragma unroll
      for (int mi = 0; mi < 4; ++mi)
#pragma unroll
        for (int nj = 0; nj < 4; ++nj)
          acc[mi][nj] = __builtin_amdgcn_mfma_f32_16x16x32_bf16(af[mi], bf[nj], acc[mi][nj], 0, 0, 0);
    }
    __syncthreads();
  }

#pragma unroll
  for (int mi = 0; mi < 4; ++mi)
#pragma unroll
    for (int nj = 0; nj < 4; ++nj) {
      int col = tn + wc * 64 + nj * 16 + lr;
      float bv = bias[col];
#pragma unroll
      for (int r = 0; r < 4; ++r) {
        int row = tm + wr * 64 + mi * 16 + lg * 4 + r;
        float v = acc[mi][nj][r] + bv;
        if (EPI == 1) v = v > 0.f ? v : 0.f;
        if (EPI == 2)
          ((float*)Cout)[(size_t)row * N + col] = v;
        else
          ((u16*)Cout)[(size_t)row * N + col] = f2bf(v);
      }
    }
}

// ---------------- causal flash attention (balanced pairs, swapped QK^T) ----------------
// QKV: (8192, 1536) bf16, cols [q | k | v] each h*64+e. att out: (8192, 512) bf16.
// Block = pair of q-chunks (p, 31-p), each 64 rows; 4 waves x 16 q-rows; KVBLK=64.
// Swapped QK^T: s = mfma(A=K, B=Q) -> lane holds q-row (lane&15), kv = nj*16+lg*4+r.
__global__ __launch_bounds__(256) void k_attn(const u16* __restrict__ QKV,
                                              u16* __restrict__ att) {
  __shared__ __align__(16) u16 lds[12288];  // K swz [0,8K) | V^T swz [8K,16K) | P 4x[16][64] swz [16K,24K)
  const int p = blockIdx.x, nh = blockIdx.y;
  const int n = nh >> 3, h = nh & 7;
  const int tid = threadIdx.x, wid = tid >> 6, lane = tid & 63;
  const int lr = lane & 15, lg = lane >> 4;
  char* lp = (char*)lds;
  const u16* Qp = QKV + (size_t)(n * 2048) * 1536 + h * 64;
  const u16* Kp = Qp + 512;
  const u16* Vp = Qp + 1024;

  const int vkv = (tid & 31) * 2;   // V staging: kv pair base
  const int vd0 = (tid >> 5) * 8;   // V staging: d chunk
  const int pwb = 16384 + wid * 2048;
  const float C2 = 0.18033688011112042f;  // log2(e)/8

  for (int ph = 0; ph < 2; ++ph) {
    const int qc = (ph == 0) ? p : 31 - p;
    const int ntiles = qc + 1;
    const int qw = qc * 64 + wid * 16;
    const int qa = qw + lr;  // this lane's q row (sequence-local)

    bf16x8 qf[2];
#pragma unroll
    for (int ks = 0; ks < 2; ++ks)
      qf[ks] = *(const bf16x8*)(Qp + (size_t)(qw + lr) * 1536 + ks * 32 + lg * 8);

    f32x4 o[4] = {};
    float mstat = NEG_INF, lstat = 0.f;

    for (int t = 0; t < ntiles; ++t) {
      const int kv0 = t * 64;
      __syncthreads();
      // stage K [64][64] swizzled via pre-swizzled global source
#pragma unroll
      for (int it = 0; it < 2; ++it) {
        int c = (wid * 2 + it) * 64 + lane;
        int row = c >> 3, ce = ((c & 7) ^ (row & 7)) * 8;
        async16(&lds[(wid * 2 + it) * 512], Kp + (size_t)(kv0 + row) * 1536 + ce);
      }
      // stage V^T [64 d][64 kv] swizzled: each lane 2 kv rows x 8 d, packed b32 writes
      {
        bf16x8 v0 = *(const bf16x8*)(Vp + (size_t)(kv0 + vkv) * 1536 + vd0);
        bf16x8 v1 = *(const bf16x8*)(Vp + (size_t)(kv0 + vkv + 1) * 1536 + vd0);
#pragma unroll
        for (int j = 0; j < 8; ++j) {
          int d = vd0 + j;
          unsigned pk = (unsigned)bfbits(v0[j]) | ((unsigned)bfbits(v1[j]) << 16);
          *(unsigned*)(lp + 8192 + d * 128 + ((vkv * 2) ^ ((d & 7) << 4))) = pk;
        }
      }
      __syncthreads();

      // S^T = K Q^T : lane holds q=lr, kv = nj*16+lg*4+r
      f32x4 s[4] = {};
#pragma unroll
      for (int nj = 0; nj < 4; ++nj) {
        int row = nj * 16 + lr;
#pragma unroll
        for (int ks = 0; ks < 2; ++ks) {
          bf16x8 kf = *(const bf16x8*)(lp + row * 128 + ((ks * 64 + lg * 16) ^ ((row & 7) << 4)));
          s[nj] = __builtin_amdgcn_mfma_f32_16x16x32_bf16(kf, qf[ks], s[nj], 0, 0, 0);
        }
      }

      // causal mask: diagonal tile is always the last one of this chunk
      if (t == ntiles - 1) {
#pragma unroll
        for (int nj = 0; nj < 4; ++nj) {
          int kvb = kv0 + nj * 16 + lg * 4;
#pragma unroll
          for (int r = 0; r < 4; ++r)
            if (kvb + r > qa) s[nj][r] = NEG_INF;
        }
      }

      // in-lane online softmax (scale 1/8 folded into exp2 factor)
      float mx = NEG_INF;
#pragma unroll
      for (int nj = 0; nj < 4; ++nj)
#pragma unroll
        for (int r = 0; r < 4; ++r) mx = fmaxf(mx, s[nj][r]);
      mx = fmaxf(mx, __shfl_xor(mx, 16));
      mx = fmaxf(mx, __shfl_xor(mx, 32));
      float mnew = fmaxf(mstat, mx);
      float corr = exp2f((mstat - mnew) * C2);
      float psum = 0.f;
#pragma unroll
      for (int nj = 0; nj < 4; ++nj)
#pragma unroll
        for (int r = 0; r < 4; ++r) {
          float pv = exp2f((s[nj][r] - mnew) * C2);
          s[nj][r] = pv;
          psum += pv;
        }
      psum += __shfl_xor(psum, 16);
      psum += __shfl_xor(psum, 32);
      lstat = lstat * corr + psum;
      mstat = mnew;

      // write P[q=lr][kv] (wave-private, swizzled): 4 consecutive kv packed -> b64
#pragma unroll
      for (int nj = 0; nj < 4; ++nj) {
        U2 val;
        val.x = (unsigned)f2bf(s[nj][0]) | ((unsigned)f2bf(s[nj][1]) << 16);
        val.y = (unsigned)f2bf(s[nj][2]) | ((unsigned)f2bf(s[nj][3]) << 16);
        *(U2*)(lp + pwb + lr * 128 + ((nj * 32 + lg * 8) ^ ((lr & 7) << 4))) = val;
      }

      // rescale o: broadcast corr from stats lane (q'=lg*4+r) within 16-group
#pragma unroll
      for (int r = 0; r < 4; ++r) {
        float cq = __shfl(corr, (lane & 48) | (lg * 4 + r));
#pragma unroll
        for (int nd = 0; nd < 4; ++nd) o[nd][r] *= cq;
      }

      // PV: o += P V  (A=P from LDS, B=V^T rows)
      bf16x8 pa[2];
#pragma unroll
      for (int ks = 0; ks < 2; ++ks)
        pa[ks] = *(const bf16x8*)(lp + pwb + lr * 128 + ((ks * 64 + lg * 16) ^ ((lr & 7) << 4)));
#pragma unroll
      for (int nd = 0; nd < 4; ++nd) {
        int row = nd * 16 + lr;
#pragma unroll
        for (int ks = 0; ks < 2; ++ks) {
          bf16x8 vf = *(const bf16x8*)(lp + 8192 + row * 128 + ((ks * 64 + lg * 16) ^ ((row & 7) << 4)));
          o[nd] = __builtin_amdgcn_mfma_f32_16x16x32_bf16(pa[ks], vf, o[nd], 0, 0, 0);
        }
      }
    }

    // epilogue: o row = q' = lg*4+r, col d = nd*16+lr
#pragma unroll
    for (int r = 0; r < 4; ++r) {
      float li = 1.0f / __shfl(lstat, (lane & 48) | (lg * 4 + r));
      size_t qrow = (size_t)(n * 2048 + qw + lg * 4 + r);
#pragma unroll
      for (int nd = 0; nd < 4; ++nd)
        att[qrow * 512 + h * 64 + nd * 16 + lr] = f2bf(o[nd][r] * li);
    }
  }
}

// ---------------- residual add + LayerNorm (D=512), optional bf16 copy ----------------
__global__ __launch_bounds__(256) void k_add_ln(const float* __restrict__ X,
                                                const float* __restrict__ Y,
                                                const float* __restrict__ gam,
                                                const float* __restrict__ bet,
                                                float* __restrict__ outf,
                                                u16* __restrict__ outb) {
  int row = blockIdx.x, t = threadIdx.x;
  const float* x = X + (size_t)row * 512;
  const float* y = Y + (size_t)row * 512;
  float v0 = x[t] + y[t];
  float v1 = x[t + 256] + y[t + 256];
  float s = v0 + v1, ss = v0 * v0 + v1 * v1;
#pragma unroll
  for (int m = 1; m < 64; m <<= 1) { s += __shfl_xor(s, m); ss += __shfl_xor(ss, m); }
  __shared__ float red[2][4];
  int wid = t >> 6;
  if ((t & 63) == 0) { red[0][wid] = s; red[1][wid] = ss; }
  __syncthreads();
  s = red[0][0] + red[0][1] + red[0][2] + red[0][3];
  ss = red[1][0] + red[1][1] + red[1][2] + red[1][3];
  float mean = s * (1.f / 512.f);
  float var = ss * (1.f / 512.f) - mean * mean;
  float rstd = rsqrtf(var + 1e-10f);
  float o0 = gam[t] * (v0 - mean) * rstd + bet[t];
  float o1 = gam[t + 256] * (v1 - mean) * rstd + bet[t + 256];
  float* of = outf + (size_t)row * 512;
  of[t] = o0;
  of[t + 256] = o1;
  if (outb) {
    u16* ob = outb + (size_t)row * 512;
    ob[t] = f2bf(o0);
    ob[t + 256] = f2bf(o1);
  }
}

extern "C" void kernel_launch(void* const* d_in, const int* in_sizes, int n_in,
                              void* d_out, int out_size, void* d_ws, size_t ws_size,
                              hipStream_t stream) {
  const float* x  = (const float*)d_in[0];
  const float* Wq = (const float*)d_in[1];
  const float* bq = (const float*)d_in[2];
  const float* Wk = (const float*)d_in[3];
  const float* bk = (const float*)d_in[4];
  const float* Wv = (const float*)d_in[5];
  const float* bv = (const float*)d_in[6];
  const float* Wo = (const float*)d_in[7];
  const float* bo = (const float*)d_in[8];
  const float* W1 = (const float*)d_in[9];
  const float* b1 = (const float*)d_in[10];
  const float* W2 = (const float*)d_in[11];
  const float* b2 = (const float*)d_in[12];
  const float* g1 = (const float*)d_in[13];
  const float* be1 = (const float*)d_in[14];
  const float* g2 = (const float*)d_in[15];
  const float* be2 = (const float*)d_in[16];
  // d_in[17] = mask: exactly causal, applied analytically.

  char* ws = (char*)d_ws;
  // region 0 [0,8M): xb -> att -> h1b (sequential lifetimes)
  u16* xb   = (u16*)(ws + 0);
  u16* attb = (u16*)(ws + 0);
  u16* h1b  = (u16*)(ws + 0);
  // region 1 [8M,~14.7M): bf16 transposed weights + packed bias (persistent)
  u16* WqkvT = (u16*)(ws + (size_t)(8u << 20));
  u16* WoT = WqkvT + 786432;
  u16* W1T = WoT + 262144;
  u16* W2T = W1T + 1048576;
  float* bqkv = (float*)(W2T + 1048576);
  // region 2 [16M,49.6M): QKV -> attproj -> ff1 (sequential lifetimes)
  u16* QKV = (u16*)(ws + (size_t)(16u << 20));
  float* attproj = (float*)(ws + (size_t)(16u << 20));
  u16* ff1 = (u16*)(ws + (size_t)(16u << 20));
  // region 3 [50M,66.8M): ffn2
  float* ffn2 = (float*)(ws + (size_t)(50u << 20));
  // h1 (fp32) parked in d_out, overwritten by final LN
  float* h1f = (float*)d_out;

  // 1) converts / transposes
  k_cvt<<<2048, 256, 0, stream>>>((const float4*)x, (uint4*)xb, 524288);
  k_transpose<<<dim3(1, 16, 8), 256, 0, stream>>>(Wq, WqkvT, 512, 64);
  k_transpose<<<dim3(1, 16, 8), 256, 0, stream>>>(Wk, WqkvT + 262144, 512, 64);
  k_transpose<<<dim3(1, 16, 8), 256, 0, stream>>>(Wv, WqkvT + 524288, 512, 64);
  k_transpose<<<dim3(8, 16, 1), 256, 0, stream>>>(Wo, WoT, 512, 512);
  k_transpose<<<dim3(32, 16, 1), 256, 0, stream>>>(W1, W1T, 512, 2048);
  k_transpose<<<dim3(8, 64, 1), 256, 0, stream>>>(W2, W2T, 2048, 512);
  k_pack_bias<<<6, 256, 0, stream>>>(bq, bk, bv, bqkv);

  // 2) QKV projection: (8192,512) @ (512,1536)
  k_gemm<0><<<dim3(64, 12), 256, 0, stream>>>(xb, WqkvT, bqkv, QKV, 8192, 1536, 512);
  // 3) causal attention (balanced pairs)
  k_attn<<<dim3(16, 32), 256, 0, stream>>>(QKV, attb);
  // 4) output projection (fp32 out)
  k_gemm<2><<<dim3(64, 4), 256, 0, stream>>>(attb, WoT, bo, attproj, 8192, 512, 512);
  // 5) h1 = LN(x + attproj)
  k_add_ln<<<8192, 256, 0, stream>>>(x, attproj, g1, be1, h1f, h1b);
  // 6) FFN
  k_gemm<1><<<dim3(64, 16), 256, 0, stream>>>(h1b, W1T, b1, ff1, 8192, 2048, 512);
  k_gemm<2><<<dim3(64, 4), 256, 0, stream>>>(ff1, W2T, b2, ffn2, 8192, 512, 2048);
  // 7) out = LN(h1 + ffn2)
  k_add_ln<<<8192, 256, 0, stream>>>(h1f, ffn2, g2, be2, (float*)d_out, nullptr);
}

// Round 3
// 218.644 us; speedup vs baseline: 1.3450x; 1.0747x over previous
//
#include <hip/hip_runtime.h>
#include <cstdint>

typedef unsigned short u16;
typedef __bf16 bf16x8 __attribute__((ext_vector_type(8)));
typedef float f32x4 __attribute__((ext_vector_type(4)));
struct __align__(8) U2 { unsigned x, y; };

#define NEG_INF (-__builtin_inff())

__device__ __forceinline__ u16 f2bf(float f) {
  unsigned u = __builtin_bit_cast(unsigned, f);
  u += 0x7FFFu + ((u >> 16) & 1u);
  return (u16)(u >> 16);
}
__device__ __forceinline__ u16 bfbits(__bf16 x) { return __builtin_bit_cast(u16, x); }
__device__ __forceinline__ unsigned pk2(float a, float b) {
  u16 lo = bfbits((__bf16)a), hi = bfbits((__bf16)b);
  return (unsigned)lo | ((unsigned)hi << 16);
}

// global->LDS async copy, 16B per lane. LDS dest is wave-uniform base + lane*16.
__device__ __forceinline__ void async16(u16* dst, const u16* src) {
  __builtin_amdgcn_global_load_lds(
      (__attribute__((address_space(1))) void*)(u16*)src,
      (__attribute__((address_space(3))) void*)dst, 16, 0, 0);
}

// ---------------- fp32 -> bf16 convert (8 elems/thread) ----------------
__global__ __launch_bounds__(256) void k_cvt(const float4* __restrict__ in,
                                             uint4* __restrict__ out, int n8) {
  int i = blockIdx.x * 256 + threadIdx.x;
  if (i >= n8) return;
  float4 a = in[2 * i], b = in[2 * i + 1];
  uint4 r;
  r.x = (unsigned)f2bf(a.x) | ((unsigned)f2bf(a.y) << 16);
  r.y = (unsigned)f2bf(a.z) | ((unsigned)f2bf(a.w) << 16);
  r.z = (unsigned)f2bf(b.x) | ((unsigned)f2bf(b.y) << 16);
  r.w = (unsigned)f2bf(b.z) | ((unsigned)f2bf(b.w) << 16);
  out[i] = r;
}

// ------------- batched transpose+convert: in (B,R,C) f32 -> out (B,C,R) bf16 -------------
__global__ __launch_bounds__(256) void k_transpose(const float* __restrict__ in,
                                                   u16* __restrict__ out, int R, int C) {
  __shared__ float t[32][65];
  int b = blockIdx.z;
  int r0 = blockIdx.y * 32, c0 = blockIdx.x * 64;
  const float* ip = in + (size_t)b * R * C;
  u16* op = out + (size_t)b * R * C;
  int tx = threadIdx.x & 63, ty = threadIdx.x >> 6;
#pragma unroll
  for (int i = 0; i < 32; i += 4) {
    int r = r0 + ty + i, c = c0 + tx;
    t[ty + i][tx] = (r < R && c < C) ? ip[(size_t)r * C + c] : 0.f;
  }
  __syncthreads();
  int cx = threadIdx.x & 31, cy = threadIdx.x >> 5;
#pragma unroll
  for (int j = 0; j < 64; j += 8) {
    int oc = c0 + cy + j, orr = r0 + cx;
    if (oc < C && orr < R) op[(size_t)oc * R + orr] = f2bf(t[cx][cy + j]);
  }
}

// merged Wq/Wk/Wv transpose: 24 batches of (512,64) -> (64,512)
__global__ __launch_bounds__(256) void k_transpose_qkv(const float* __restrict__ Wq,
                                                       const float* __restrict__ Wk,
                                                       const float* __restrict__ Wv,
                                                       u16* __restrict__ out) {
  __shared__ float t[32][65];
  int z = blockIdx.z;
  const float* W = (z < 8) ? Wq : (z < 16) ? Wk : Wv;
  const float* ip = W + (size_t)(z & 7) * 32768;
  u16* op = out + (size_t)z * 32768;
  int r0 = blockIdx.y * 32;
  int tx = threadIdx.x & 63, ty = threadIdx.x >> 6;
#pragma unroll
  for (int i = 0; i < 32; i += 4)
    t[ty + i][tx] = ip[(size_t)(r0 + ty + i) * 64 + tx];
  __syncthreads();
  int cx = threadIdx.x & 31, cy = threadIdx.x >> 5;
#pragma unroll
  for (int j = 0; j < 64; j += 8)
    op[(size_t)(cy + j) * 512 + r0 + cx] = f2bf(t[cx][cy + j]);
}

__global__ __launch_bounds__(256) void k_pack_bias(const float* __restrict__ bq,
                                                   const float* __restrict__ bk,
                                                   const float* __restrict__ bv,
                                                   float* __restrict__ bpk) {
  int i = blockIdx.x * 256 + threadIdx.x;
  if (i < 1536) {
    int m = i >> 9, r = i & 511;
    const float* B = (m == 0) ? bq : (m == 1) ? bk : bv;
    bpk[i] = B[r];
  }
}

// ---------------- bf16 MFMA GEMM: C(M,N) = A(M,K) * BT(N,K)^T + bias ----------------
// EPI: 0 = bf16 store, 1 = bf16 store + relu, 2 = f32 store
template <int EPI>
__global__ __launch_bounds__(256) void k_gemm(const u16* __restrict__ A,
                                              const u16* __restrict__ BT,
                                              const float* __restrict__ bias,
                                              void* __restrict__ Cout,
                                              int M, int N, int Kd) {
  __shared__ __align__(16) u16 lds[16384];  // A tile [128][64] + B tile [128][64], XOR-swizzled
  const int tid = threadIdx.x, wid = tid >> 6, lane = tid & 63;
  const int lr = lane & 15, lg = lane >> 4;
  const int wr = wid >> 1, wc = wid & 1;
  const int tm = blockIdx.x * 128, tn = blockIdx.y * 128;
  const char* lp = (const char*)lds;

  f32x4 acc[4][4] = {};

  const int srow = lane >> 3;            // row within 8-row staging region
  const int kb = (lane & 7) ^ srow;      // pre-swizzled source chunk

  for (int kt = 0; kt < Kd; kt += 64) {
#pragma unroll
    for (int it = 0; it < 4; ++it) {
      int rid = wid * 4 + it;
      int row = rid * 8 + srow;
      async16(&lds[rid * 512], A + (size_t)(tm + row) * Kd + kt + kb * 8);
      async16(&lds[8192 + rid * 512], BT + (size_t)(tn + row) * Kd + kt + kb * 8);
    }
    __syncthreads();
#pragma unroll
    for (int ks = 0; ks < 2; ++ks) {
      const int kbyte = ks * 64 + lg * 16;
      bf16x8 af[4], bf[4];
#pragma unroll
      for (int mi = 0; mi < 4; ++mi) {
        int row = wr * 64 + mi * 16 + lr;
        af[mi] = *(const bf16x8*)(lp + row * 128 + (kbyte ^ ((row & 7) << 4)));
      }
#pragma unroll
      for (int nj = 0; nj < 4; ++nj) {
        int row = wc * 64 + nj * 16 + lr;
        bf[nj] = *(const bf16x8*)(lp + 16384 + row * 128 + (kbyte ^ ((row & 7) << 4)));
      }
#pragma unroll
      for (int mi = 0; mi < 4; ++mi)
#pragma unroll
        for (int nj = 0; nj < 4; ++nj)
          acc[mi][nj] = __builtin_amdgcn_mfma_f32_16x16x32_bf16(af[mi], bf[nj], acc[mi][nj], 0, 0, 0);
    }
    __syncthreads();
  }

#pragma unroll
  for (int mi = 0; mi < 4; ++mi)
#pragma unroll
    for (int nj = 0; nj < 4; ++nj) {
      int col = tn + wc * 64 + nj * 16 + lr;
      float bv = bias[col];
#pragma unroll
      for (int r = 0; r < 4; ++r) {
        int row = tm + wr * 64 + mi * 16 + lg * 4 + r;
        float v = acc[mi][nj][r] + bv;
        if (EPI == 1) v = v > 0.f ? v : 0.f;
        if (EPI == 2)
          ((float*)Cout)[(size_t)row * N + col] = v;
        else
          ((u16*)Cout)[(size_t)row * N + col] = f2bf(v);
      }
    }
}

// ---------------- causal flash attention ----------------
// Balanced pairs, swapped QK^T, double-buffered K/V prefetch, XCD-local heads.
// QKV: (8192, 1536) bf16, cols [q | k | v] each h*64+e. att out: (8192, 512) bf16.
__global__ __launch_bounds__(256) void k_attn(const u16* __restrict__ QKV,
                                              u16* __restrict__ att) {
  // LDS bytes: K dbuf [0,16K) | V^T dbuf [16K,32K) | P 4x[16][64] [32K,40K)
  __shared__ __align__(16) u16 lds[20480];
  // XCD-bijective remap: 512 blocks = 8 XCD x 64; all 16 p of 4 heads on one XCD.
  const int lin = blockIdx.x;
  const int L = (lin & 7) * 64 + (lin >> 3);
  const int p = L & 15, nh = L >> 4;
  const int n = nh >> 3, h = nh & 7;
  const int tid = threadIdx.x, wid = tid >> 6, lane = tid & 63;
  const int lr = lane & 15, lg = lane >> 4;
  char* lp = (char*)lds;
  const u16* Qp = QKV + (size_t)(n * 2048) * 1536 + h * 64;
  const u16* Kp = Qp + 512;
  const u16* Vp = Qp + 1024;

  const int vkv = (tid & 31) * 2;   // V staging: kv pair base
  const int vd0 = (tid >> 5) * 8;   // V staging: d chunk
  const int pwb = 32768 + wid * 2048;  // byte base of this wave's P
  const float C2 = 0.18033688011112042f;  // log2(e)/8

  for (int ph = 0; ph < 2; ++ph) {
    const int qc = (ph == 0) ? p : 31 - p;
    const int ntiles = qc + 1;
    const int qw = qc * 64 + wid * 16;
    const int qa = qw + lr;  // this lane's q row (sequence-local)

    bf16x8 qf[2];
#pragma unroll
    for (int ks = 0; ks < 2; ++ks)
      qf[ks] = *(const bf16x8*)(Qp + (size_t)(qw + lr) * 1536 + ks * 32 + lg * 8);

    f32x4 o[4] = {};
    float mstat = NEG_INF, lstat = 0.f;
    int cur = 0;

    // prologue: stage tile 0 into buffer 0
#pragma unroll
    for (int it = 0; it < 2; ++it) {
      int c = (wid * 2 + it) * 64 + lane;
      int row = c >> 3, ce = ((c & 7) ^ (row & 7)) * 8;
      async16(&lds[(wid * 2 + it) * 512], Kp + (size_t)row * 1536 + ce);
    }
    {
      bf16x8 v0 = *(const bf16x8*)(Vp + (size_t)vkv * 1536 + vd0);
      bf16x8 v1 = *(const bf16x8*)(Vp + (size_t)(vkv + 1) * 1536 + vd0);
#pragma unroll
      for (int j = 0; j < 8; ++j) {
        int d = vd0 + j;
        unsigned pk = (unsigned)bfbits(v0[j]) | ((unsigned)bfbits(v1[j]) << 16);
        *(unsigned*)(lp + 16384 + d * 128 + ((vkv * 2) ^ ((d & 7) << 4))) = pk;
      }
    }
    __syncthreads();

    for (int t = 0; t < ntiles; ++t) {
      const int nxt = cur ^ 1;
      bf16x8 va, vb;
      const bool pre = (t + 1 < ntiles);
      if (pre) {
        const int kvn = (t + 1) * 64;
        // issue K(t+1) -> LDS[alt] and V(t+1) -> regs; latency hides under compute
#pragma unroll
        for (int it = 0; it < 2; ++it) {
          int c = (wid * 2 + it) * 64 + lane;
          int row = c >> 3, ce = ((c & 7) ^ (row & 7)) * 8;
          async16(&lds[nxt * 4096 + (wid * 2 + it) * 512],
                  Kp + (size_t)(kvn + row) * 1536 + ce);
        }
        va = *(const bf16x8*)(Vp + (size_t)(kvn + vkv) * 1536 + vd0);
        vb = *(const bf16x8*)(Vp + (size_t)(kvn + vkv + 1) * 1536 + vd0);
      }

      // S^T = K Q^T : lane holds q=lr, kv = nj*16+lg*4+r
      const int kv0 = t * 64;
      f32x4 s[4] = {};
#pragma unroll
      for (int nj = 0; nj < 4; ++nj) {
        int row = nj * 16 + lr;
#pragma unroll
        for (int ks = 0; ks < 2; ++ks) {
          bf16x8 kf = *(const bf16x8*)(lp + cur * 8192 + row * 128 +
                                       ((ks * 64 + lg * 16) ^ ((row & 7) << 4)));
          s[nj] = __builtin_amdgcn_mfma_f32_16x16x32_bf16(kf, qf[ks], s[nj], 0, 0, 0);
        }
      }

      // causal mask: diagonal tile is always the last one of this chunk
      if (t == ntiles - 1) {
#pragma unroll
        for (int nj = 0; nj < 4; ++nj) {
          int kvb = kv0 + nj * 16 + lg * 4;
#pragma unroll
          for (int r = 0; r < 4; ++r)
            if (kvb + r > qa) s[nj][r] = NEG_INF;
        }
      }

      // in-lane online softmax (scale 1/8 folded into exp2 factor)
      float mx = NEG_INF;
#pragma unroll
      for (int nj = 0; nj < 4; ++nj)
#pragma unroll
        for (int r = 0; r < 4; ++r) mx = fmaxf(mx, s[nj][r]);
      mx = fmaxf(mx, __shfl_xor(mx, 16));
      mx = fmaxf(mx, __shfl_xor(mx, 32));
      float mnew = fmaxf(mstat, mx);
      float corr = exp2f((mstat - mnew) * C2);
      float psum = 0.f;
#pragma unroll
      for (int nj = 0; nj < 4; ++nj)
#pragma unroll
        for (int r = 0; r < 4; ++r) {
          float pv = exp2f((s[nj][r] - mnew) * C2);
          s[nj][r] = pv;
          psum += pv;
        }
      psum += __shfl_xor(psum, 16);
      psum += __shfl_xor(psum, 32);
      lstat = lstat * corr + psum;
      mstat = mnew;

      // write P[q=lr][kv] (wave-private, swizzled): 4 consecutive kv packed -> b64
#pragma unroll
      for (int nj = 0; nj < 4; ++nj) {
        U2 val;
        val.x = pk2(s[nj][0], s[nj][1]);
        val.y = pk2(s[nj][2], s[nj][3]);
        *(U2*)(lp + pwb + lr * 128 + ((nj * 32 + lg * 8) ^ ((lr & 7) << 4))) = val;
      }

      // rescale o: broadcast corr from stats lane (q'=lg*4+r) within 16-group
#pragma unroll
      for (int r = 0; r < 4; ++r) {
        float cq = __shfl(corr, (lane & 48) | (lg * 4 + r));
#pragma unroll
        for (int nd = 0; nd < 4; ++nd) o[nd][r] *= cq;
      }

      // PV: o += P V  (A=P from LDS, B=V^T rows)
      bf16x8 pa[2];
#pragma unroll
      for (int ks = 0; ks < 2; ++ks)
        pa[ks] = *(const bf16x8*)(lp + pwb + lr * 128 +
                                  ((ks * 64 + lg * 16) ^ ((lr & 7) << 4)));
#pragma unroll
      for (int nd = 0; nd < 4; ++nd) {
        int row = nd * 16 + lr;
#pragma unroll
        for (int ks = 0; ks < 2; ++ks) {
          bf16x8 vf = *(const bf16x8*)(lp + 16384 + cur * 8192 + row * 128 +
                                       ((ks * 64 + lg * 16) ^ ((row & 7) << 4)));
          o[nd] = __builtin_amdgcn_mfma_f32_16x16x32_bf16(pa[ks], vf, o[nd], 0, 0, 0);
        }
      }

      // land V(t+1) into LDS[alt] after compute (global latency already covered)
      if (pre) {
#pragma unroll
        for (int j = 0; j < 8; ++j) {
          int d = vd0 + j;
          unsigned pk = (unsigned)bfbits(va[j]) | ((unsigned)bfbits(vb[j]) << 16);
          *(unsigned*)(lp + 16384 + nxt * 8192 + d * 128 + ((vkv * 2) ^ ((d & 7) << 4))) = pk;
        }
      }
      __syncthreads();  // compiler drains vmcnt (K async) + lgkm before barrier
      cur = nxt;
    }

    // epilogue: o row = q' = lg*4+r, col d = nd*16+lr
#pragma unroll
    for (int r = 0; r < 4; ++r) {
      float li = 1.0f / __shfl(lstat, (lane & 48) | (lg * 4 + r));
      size_t qrow = (size_t)(n * 2048 + qw + lg * 4 + r);
#pragma unroll
      for (int nd = 0; nd < 4; ++nd)
        att[qrow * 512 + h * 64 + nd * 16 + lr] = f2bf(o[nd][r] * li);
    }
  }
}

// ---------------- residual add + LayerNorm (D=512), optional bf16 copy ----------------
__global__ __launch_bounds__(256) void k_add_ln(const float* __restrict__ X,
                                                const float* __restrict__ Y,
                                                const float* __restrict__ gam,
                                                const float* __restrict__ bet,
                                                float* __restrict__ outf,
                                                u16* __restrict__ outb) {
  int row = blockIdx.x, t = threadIdx.x;
  const float* x = X + (size_t)row * 512;
  const float* y = Y + (size_t)row * 512;
  float v0 = x[t] + y[t];
  float v1 = x[t + 256] + y[t + 256];
  float s = v0 + v1, ss = v0 * v0 + v1 * v1;
#pragma unroll
  for (int m = 1; m < 64; m <<= 1) { s += __shfl_xor(s, m); ss += __shfl_xor(ss, m); }
  __shared__ float red[2][4];
  int wid = t >> 6;
  if ((t & 63) == 0) { red[0][wid] = s; red[1][wid] = ss; }
  __syncthreads();
  s = red[0][0] + red[0][1] + red[0][2] + red[0][3];
  ss = red[1][0] + red[1][1] + red[1][2] + red[1][3];
  float mean = s * (1.f / 512.f);
  float var = ss * (1.f / 512.f) - mean * mean;
  float rstd = rsqrtf(var + 1e-10f);
  float o0 = gam[t] * (v0 - mean) * rstd + bet[t];
  float o1 = gam[t + 256] * (v1 - mean) * rstd + bet[t + 256];
  float* of = outf + (size_t)row * 512;
  of[t] = o0;
  of[t + 256] = o1;
  if (outb) {
    u16* ob = outb + (size_t)row * 512;
    ob[t] = f2bf(o0);
    ob[t + 256] = f2bf(o1);
  }
}

extern "C" void kernel_launch(void* const* d_in, const int* in_sizes, int n_in,
                              void* d_out, int out_size, void* d_ws, size_t ws_size,
                              hipStream_t stream) {
  const float* x  = (const float*)d_in[0];
  const float* Wq = (const float*)d_in[1];
  const float* bq = (const float*)d_in[2];
  const float* Wk = (const float*)d_in[3];
  const float* bk = (const float*)d_in[4];
  const float* Wv = (const float*)d_in[5];
  const float* bv = (const float*)d_in[6];
  const float* Wo = (const float*)d_in[7];
  const float* bo = (const float*)d_in[8];
  const float* W1 = (const float*)d_in[9];
  const float* b1 = (const float*)d_in[10];
  const float* W2 = (const float*)d_in[11];
  const float* b2 = (const float*)d_in[12];
  const float* g1 = (const float*)d_in[13];
  const float* be1 = (const float*)d_in[14];
  const float* g2 = (const float*)d_in[15];
  const float* be2 = (const float*)d_in[16];
  // d_in[17] = mask: exactly causal, applied analytically.

  char* ws = (char*)d_ws;
  // region 0 [0,8M): xb -> att -> h1b (sequential lifetimes)
  u16* xb   = (u16*)(ws + 0);
  u16* attb = (u16*)(ws + 0);
  u16* h1b  = (u16*)(ws + 0);
  // region 1 [8M,~14.7M): bf16 transposed weights + packed bias (persistent)
  u16* WqkvT = (u16*)(ws + (size_t)(8u << 20));
  u16* WoT = WqkvT + 786432;
  u16* W1T = WoT + 262144;
  u16* W2T = W1T + 1048576;
  float* bqkv = (float*)(W2T + 1048576);
  // region 2 [16M,49.6M): QKV -> attproj -> ff1 (sequential lifetimes)
  u16* QKV = (u16*)(ws + (size_t)(16u << 20));
  float* attproj = (float*)(ws + (size_t)(16u << 20));
  u16* ff1 = (u16*)(ws + (size_t)(16u << 20));
  // region 3 [50M,66.8M): ffn2
  float* ffn2 = (float*)(ws + (size_t)(50u << 20));
  // h1 (fp32) parked in d_out, overwritten by final LN
  float* h1f = (float*)d_out;

  // 1) converts / transposes
  k_cvt<<<2048, 256, 0, stream>>>((const float4*)x, (uint4*)xb, 524288);
  k_transpose_qkv<<<dim3(1, 16, 24), 256, 0, stream>>>(Wq, Wk, Wv, WqkvT);
  k_transpose<<<dim3(8, 16, 1), 256, 0, stream>>>(Wo, WoT, 512, 512);
  k_transpose<<<dim3(32, 16, 1), 256, 0, stream>>>(W1, W1T, 512, 2048);
  k_transpose<<<dim3(8, 64, 1), 256, 0, stream>>>(W2, W2T, 2048, 512);
  k_pack_bias<<<6, 256, 0, stream>>>(bq, bk, bv, bqkv);

  // 2) QKV projection: (8192,512) @ (512,1536)
  k_gemm<0><<<dim3(64, 12), 256, 0, stream>>>(xb, WqkvT, bqkv, QKV, 8192, 1536, 512);
  // 3) causal attention (balanced pairs, XCD-local)
  k_attn<<<512, 256, 0, stream>>>(QKV, attb);
  // 4) output projection (fp32 out)
  k_gemm<2><<<dim3(64, 4), 256, 0, stream>>>(attb, WoT, bo, attproj, 8192, 512, 512);
  // 5) h1 = LN(x + attproj)
  k_add_ln<<<8192, 256, 0, stream>>>(x, attproj, g1, be1, h1f, h1b);
  // 6) FFN
  k_gemm<1><<<dim3(64, 16), 256, 0, stream>>>(h1b, W1T, b1, ff1, 8192, 2048, 512);
  k_gemm<2><<<dim3(64, 4), 256, 0, stream>>>(ff1, W2T, b2, ffn2, 8192, 512, 2048);
  // 7) out = LN(h1 + ffn2)
  k_add_ln<<<8192, 256, 0, stream>>>(h1f, ffn2, g2, be2, (float*)d_out, nullptr);
}

// Round 4
// 218.009 us; speedup vs baseline: 1.3490x; 1.0029x over previous
//
#include <hip/hip_runtime.h>
#include <cstdint>

typedef unsigned short u16;
typedef __bf16 bf16x8 __attribute__((ext_vector_type(8)));
typedef float f32x4 __attribute__((ext_vector_type(4)));
struct __align__(8) U2 { unsigned x, y; };

#define NEG_INF (-__builtin_inff())

__device__ __forceinline__ u16 f2bf(float f) {
  unsigned u = __builtin_bit_cast(unsigned, f);
  u += 0x7FFFu + ((u >> 16) & 1u);
  return (u16)(u >> 16);
}
__device__ __forceinline__ u16 bfbits(__bf16 x) { return __builtin_bit_cast(u16, x); }
__device__ __forceinline__ unsigned pk2(float a, float b) {
  u16 lo = bfbits((__bf16)a), hi = bfbits((__bf16)b);
  return (unsigned)lo | ((unsigned)hi << 16);
}

// global->LDS async copy, 16B per lane. LDS dest is wave-uniform base + lane*16.
__device__ __forceinline__ void async16(u16* dst, const u16* src) {
  __builtin_amdgcn_global_load_lds(
      (__attribute__((address_space(1))) void*)(u16*)src,
      (__attribute__((address_space(3))) void*)dst, 16, 0, 0);
}

// ---------------- fp32 -> bf16 convert (8 elems/thread) ----------------
__global__ __launch_bounds__(256) void k_cvt(const float4* __restrict__ in,
                                             uint4* __restrict__ out, int n8) {
  int i = blockIdx.x * 256 + threadIdx.x;
  if (i >= n8) return;
  float4 a = in[2 * i], b = in[2 * i + 1];
  uint4 r;
  r.x = (unsigned)f2bf(a.x) | ((unsigned)f2bf(a.y) << 16);
  r.y = (unsigned)f2bf(a.z) | ((unsigned)f2bf(a.w) << 16);
  r.z = (unsigned)f2bf(b.x) | ((unsigned)f2bf(b.y) << 16);
  r.w = (unsigned)f2bf(b.z) | ((unsigned)f2bf(b.w) << 16);
  out[i] = r;
}

// ------------- batched transpose+convert: in (B,R,C) f32 -> out (B,C,R) bf16 -------------
__global__ __launch_bounds__(256) void k_transpose(const float* __restrict__ in,
                                                   u16* __restrict__ out, int R, int C) {
  __shared__ float t[32][65];
  int b = blockIdx.z;
  int r0 = blockIdx.y * 32, c0 = blockIdx.x * 64;
  const float* ip = in + (size_t)b * R * C;
  u16* op = out + (size_t)b * R * C;
  int tx = threadIdx.x & 63, ty = threadIdx.x >> 6;
#pragma unroll
  for (int i = 0; i < 32; i += 4) {
    int r = r0 + ty + i, c = c0 + tx;
    t[ty + i][tx] = (r < R && c < C) ? ip[(size_t)r * C + c] : 0.f;
  }
  __syncthreads();
  int cx = threadIdx.x & 31, cy = threadIdx.x >> 5;
#pragma unroll
  for (int j = 0; j < 64; j += 8) {
    int oc = c0 + cy + j, orr = r0 + cx;
    if (oc < C && orr < R) op[(size_t)oc * R + orr] = f2bf(t[cx][cy + j]);
  }
}

// merged Wq/Wk/Wv transpose: 24 batches of (512,64) -> (64,512)
__global__ __launch_bounds__(256) void k_transpose_qkv(const float* __restrict__ Wq,
                                                       const float* __restrict__ Wk,
                                                       const float* __restrict__ Wv,
                                                       u16* __restrict__ out) {
  __shared__ float t[32][65];
  int z = blockIdx.z;
  const float* W = (z < 8) ? Wq : (z < 16) ? Wk : Wv;
  const float* ip = W + (size_t)(z & 7) * 32768;
  u16* op = out + (size_t)z * 32768;
  int r0 = blockIdx.y * 32;
  int tx = threadIdx.x & 63, ty = threadIdx.x >> 6;
#pragma unroll
  for (int i = 0; i < 32; i += 4)
    t[ty + i][tx] = ip[(size_t)(r0 + ty + i) * 64 + tx];
  __syncthreads();
  int cx = threadIdx.x & 31, cy = threadIdx.x >> 5;
#pragma unroll
  for (int j = 0; j < 64; j += 8)
    op[(size_t)(cy + j) * 512 + r0 + cx] = f2bf(t[cx][cy + j]);
}

__global__ __launch_bounds__(256) void k_pack_bias(const float* __restrict__ bq,
                                                   const float* __restrict__ bk,
                                                   const float* __restrict__ bv,
                                                   float* __restrict__ bpk) {
  int i = blockIdx.x * 256 + threadIdx.x;
  if (i < 1536) {
    int m = i >> 9, r = i & 511;
    const float* B = (m == 0) ? bq : (m == 1) ? bk : bv;
    bpk[i] = B[r];
  }
}

// ---------------- bf16 MFMA GEMM: C(M,N) = A(M,K) * BT(N,K)^T + bias ----------------
// EPI: 0 = bf16 store, 1 = bf16 store + relu, 2 = f32 store
// BN: 128 (wave tile 64x64) or 64 (wave tile 64x32, 2x blocks for small N)
template <int EPI, int BN>
__global__ __launch_bounds__(256) void k_gemm(const u16* __restrict__ A,
                                              const u16* __restrict__ BT,
                                              const float* __restrict__ bias,
                                              void* __restrict__ Cout,
                                              int M, int N, int Kd) {
  __shared__ __align__(16) u16 lds[8192 + BN * 64];  // A [128][64] + B [BN][64], XOR-swizzled
  constexpr int NFR = BN / 32;    // N frags per wave
  constexpr int BITER = BN / 32;  // B staging iters per wave
  const int tid = threadIdx.x, wid = tid >> 6, lane = tid & 63;
  const int lr = lane & 15, lg = lane >> 4;
  const int wr = wid >> 1, wc = wid & 1;
  const int tm = blockIdx.x * 128, tn = blockIdx.y * BN;
  const char* lp = (const char*)lds;

  f32x4 acc[4][NFR] = {};

  const int srow = lane >> 3;            // row within 8-row staging region
  const int kb = (lane & 7) ^ srow;      // pre-swizzled source chunk

  for (int kt = 0; kt < Kd; kt += 64) {
#pragma unroll
    for (int it = 0; it < 4; ++it) {
      int rid = wid * 4 + it;
      int row = rid * 8 + srow;
      async16(&lds[rid * 512], A + (size_t)(tm + row) * Kd + kt + kb * 8);
    }
#pragma unroll
    for (int it = 0; it < BITER; ++it) {
      int rid = wid * BITER + it;
      int row = rid * 8 + srow;
      async16(&lds[8192 + rid * 512], BT + (size_t)(tn + row) * Kd + kt + kb * 8);
    }
    __syncthreads();
#pragma unroll
    for (int ks = 0; ks < 2; ++ks) {
      const int kbyte = ks * 64 + lg * 16;
      bf16x8 af[4], bfr[NFR];
#pragma unroll
      for (int mi = 0; mi < 4; ++mi) {
        int row = wr * 64 + mi * 16 + lr;
        af[mi] = *(const bf16x8*)(lp + row * 128 + (kbyte ^ ((row & 7) << 4)));
      }
#pragma unroll
      for (int nj = 0; nj < NFR; ++nj) {
        int row = wc * (BN / 2) + nj * 16 + lr;
        bfr[nj] = *(const bf16x8*)(lp + 16384 + row * 128 + (kbyte ^ ((row & 7) << 4)));
      }
#pragma unroll
      for (int mi = 0; mi < 4; ++mi)
#pragma unroll
        for (int nj = 0; nj < NFR; ++nj)
          acc[mi][nj] = __builtin_amdgcn_mfma_f32_16x16x32_bf16(af[mi], bfr[nj], acc[mi][nj], 0, 0, 0);
    }
    __syncthreads();
  }

#pragma unroll
  for (int mi = 0; mi < 4; ++mi)
#pragma unroll
    for (int nj = 0; nj < NFR; ++nj) {
      int col = tn + wc * (BN / 2) + nj * 16 + lr;
      float bv = bias[col];
#pragma unroll
      for (int r = 0; r < 4; ++r) {
        int row = tm + wr * 64 + mi * 16 + lg * 4 + r;
        float v = acc[mi][nj][r] + bv;
        if (EPI == 1) v = v > 0.f ? v : 0.f;
        if (EPI == 2)
          ((float*)Cout)[(size_t)row * N + col] = v;
        else
          ((u16*)Cout)[(size_t)row * N + col] = f2bf(v);
      }
    }
}

// ---------------- causal flash attention ----------------
// 1024 blocks: one 64-row q-chunk each; 4 waves x 16 q-rows; KVBLK=64, dbuf K/V.
// XCD-bijective remap + per-CU balanced round order (fwd,rev,fwd,rev).
// QKV: (8192, 1536) bf16, cols [q | k | v] each h*64+e. att out: (8192, 512) bf16.
__global__ __launch_bounds__(256) void k_attn(const u16* __restrict__ QKV,
                                              u16* __restrict__ att) {
  // LDS bytes: K dbuf [0,16K) | V^T dbuf [16K,32K) | P 4x[16][64] [32K,40K)
  __shared__ __align__(16) u16 lds[20480];
  const int lin = blockIdx.x;
  const int xcd = lin & 7, j = lin >> 3;    // 8 XCDs x 128 blocks
  const int rnd = j >> 5, i = j & 31;       // 4 rounds x 32 (one per CU)
  const int qc = (rnd & 1) ? 31 - i : i;    // per-CU totals: qc sums to 66 tiles
  const int nh = xcd * 4 + rnd;             // 4 heads per XCD -> K/V set 2MB < L2
  const int n = nh >> 3, h = nh & 7;
  const int tid = threadIdx.x, wid = tid >> 6, lane = tid & 63;
  const int lr = lane & 15, lg = lane >> 4;
  char* lp = (char*)lds;
  const u16* Qp = QKV + (size_t)(n * 2048) * 1536 + h * 64;
  const u16* Kp = Qp + 512;
  const u16* Vp = Qp + 1024;

  const int vkv = (tid & 31) * 2;   // V staging: kv pair base
  const int vd0 = (tid >> 5) * 8;   // V staging: d chunk
  const int pwb = 32768 + wid * 2048;  // byte base of this wave's P
  const float C2 = 0.18033688011112042f;  // log2(e)/8

  const int ntiles = qc + 1;
  const int qw = qc * 64 + wid * 16;
  const int qa = qw + lr;  // this lane's q row (sequence-local)

  bf16x8 qf[2];
#pragma unroll
  for (int ks = 0; ks < 2; ++ks)
    qf[ks] = *(const bf16x8*)(Qp + (size_t)(qw + lr) * 1536 + ks * 32 + lg * 8);

  f32x4 o[4] = {};
  float mstat = NEG_INF, lstat = 0.f;
  int cur = 0;

  // prologue: stage tile 0 into buffer 0
#pragma unroll
  for (int it = 0; it < 2; ++it) {
    int c = (wid * 2 + it) * 64 + lane;
    int row = c >> 3, ce = ((c & 7) ^ (row & 7)) * 8;
    async16(&lds[(wid * 2 + it) * 512], Kp + (size_t)row * 1536 + ce);
  }
  {
    bf16x8 v0 = *(const bf16x8*)(Vp + (size_t)vkv * 1536 + vd0);
    bf16x8 v1 = *(const bf16x8*)(Vp + (size_t)(vkv + 1) * 1536 + vd0);
#pragma unroll
    for (int jj = 0; jj < 8; ++jj) {
      int d = vd0 + jj;
      unsigned pk = (unsigned)bfbits(v0[jj]) | ((unsigned)bfbits(v1[jj]) << 16);
      *(unsigned*)(lp + 16384 + d * 128 + ((vkv * 2) ^ ((d & 7) << 4))) = pk;
    }
  }
  __syncthreads();

  for (int t = 0; t < ntiles; ++t) {
    const int nxt = cur ^ 1;
    bf16x8 va, vb;
    const bool pre = (t + 1 < ntiles);
    if (pre) {
      const int kvn = (t + 1) * 64;
      // issue K(t+1) -> LDS[alt] and V(t+1) -> regs; latency hides under compute
#pragma unroll
      for (int it = 0; it < 2; ++it) {
        int c = (wid * 2 + it) * 64 + lane;
        int row = c >> 3, ce = ((c & 7) ^ (row & 7)) * 8;
        async16(&lds[nxt * 4096 + (wid * 2 + it) * 512],
                Kp + (size_t)(kvn + row) * 1536 + ce);
      }
      va = *(const bf16x8*)(Vp + (size_t)(kvn + vkv) * 1536 + vd0);
      vb = *(const bf16x8*)(Vp + (size_t)(kvn + vkv + 1) * 1536 + vd0);
    }

    // S^T = K Q^T : lane holds q=lr, kv = nj*16+lg*4+r
    const int kv0 = t * 64;
    f32x4 s[4] = {};
#pragma unroll
    for (int nj = 0; nj < 4; ++nj) {
      int row = nj * 16 + lr;
#pragma unroll
      for (int ks = 0; ks < 2; ++ks) {
        bf16x8 kf = *(const bf16x8*)(lp + cur * 8192 + row * 128 +
                                     ((ks * 64 + lg * 16) ^ ((row & 7) << 4)));
        s[nj] = __builtin_amdgcn_mfma_f32_16x16x32_bf16(kf, qf[ks], s[nj], 0, 0, 0);
      }
    }

    // causal mask: diagonal tile is always the last one of this chunk
    if (t == ntiles - 1) {
#pragma unroll
      for (int nj = 0; nj < 4; ++nj) {
        int kvb = kv0 + nj * 16 + lg * 4;
#pragma unroll
        for (int r = 0; r < 4; ++r)
          if (kvb + r > qa) s[nj][r] = NEG_INF;
      }
    }

    // in-lane online softmax (scale 1/8 folded into exp2 factor)
    float mx = NEG_INF;
#pragma unroll
    for (int nj = 0; nj < 4; ++nj)
#pragma unroll
      for (int r = 0; r < 4; ++r) mx = fmaxf(mx, s[nj][r]);
    mx = fmaxf(mx, __shfl_xor(mx, 16));
    mx = fmaxf(mx, __shfl_xor(mx, 32));
    float mnew = fmaxf(mstat, mx);
    float corr = exp2f((mstat - mnew) * C2);
    float psum = 0.f;
#pragma unroll
    for (int nj = 0; nj < 4; ++nj)
#pragma unroll
      for (int r = 0; r < 4; ++r) {
        float pv = exp2f((s[nj][r] - mnew) * C2);
        s[nj][r] = pv;
        psum += pv;
      }
    psum += __shfl_xor(psum, 16);
    psum += __shfl_xor(psum, 32);
    lstat = lstat * corr + psum;
    mstat = mnew;

    // write P[q=lr][kv] (wave-private, swizzled): 4 consecutive kv packed -> b64
#pragma unroll
    for (int nj = 0; nj < 4; ++nj) {
      U2 val;
      val.x = pk2(s[nj][0], s[nj][1]);
      val.y = pk2(s[nj][2], s[nj][3]);
      *(U2*)(lp + pwb + lr * 128 + ((nj * 32 + lg * 8) ^ ((lr & 7) << 4))) = val;
    }

    // rescale o: broadcast corr from stats lane (q'=lg*4+r) within 16-group
#pragma unroll
    for (int r = 0; r < 4; ++r) {
      float cq = __shfl(corr, (lane & 48) | (lg * 4 + r));
#pragma unroll
      for (int nd = 0; nd < 4; ++nd) o[nd][r] *= cq;
    }

    // PV: o += P V  (A=P from LDS, B=V^T rows)
    bf16x8 pa[2];
#pragma unroll
    for (int ks = 0; ks < 2; ++ks)
      pa[ks] = *(const bf16x8*)(lp + pwb + lr * 128 +
                                ((ks * 64 + lg * 16) ^ ((lr & 7) << 4)));
#pragma unroll
    for (int nd = 0; nd < 4; ++nd) {
      int row = nd * 16 + lr;
#pragma unroll
      for (int ks = 0; ks < 2; ++ks) {
        bf16x8 vf = *(const bf16x8*)(lp + 16384 + cur * 8192 + row * 128 +
                                     ((ks * 64 + lg * 16) ^ ((row & 7) << 4)));
        o[nd] = __builtin_amdgcn_mfma_f32_16x16x32_bf16(pa[ks], vf, o[nd], 0, 0, 0);
      }
    }

    // land V(t+1) into LDS[alt] after compute (global latency already covered)
    if (pre) {
#pragma unroll
      for (int jj = 0; jj < 8; ++jj) {
        int d = vd0 + jj;
        unsigned pk = (unsigned)bfbits(va[jj]) | ((unsigned)bfbits(vb[jj]) << 16);
        *(unsigned*)(lp + 16384 + nxt * 8192 + d * 128 + ((vkv * 2) ^ ((d & 7) << 4))) = pk;
      }
    }
    __syncthreads();  // compiler drains vmcnt (K async) + lgkm before barrier
    cur = nxt;
  }

  // epilogue: o row = q' = lg*4+r, col d = nd*16+lr
#pragma unroll
  for (int r = 0; r < 4; ++r) {
    float li = 1.0f / __shfl(lstat, (lane & 48) | (lg * 4 + r));
    size_t qrow = (size_t)(n * 2048 + qw + lg * 4 + r);
#pragma unroll
    for (int nd = 0; nd < 4; ++nd)
      att[qrow * 512 + h * 64 + nd * 16 + lr] = f2bf(o[nd][r] * li);
  }
}

// ---------------- residual add + LayerNorm (D=512), optional bf16 copy ----------------
__global__ __launch_bounds__(256) void k_add_ln(const float* __restrict__ X,
                                                const float* __restrict__ Y,
                                                const float* __restrict__ gam,
                                                const float* __restrict__ bet,
                                                float* __restrict__ outf,
                                                u16* __restrict__ outb) {
  int row = blockIdx.x, t = threadIdx.x;
  const float* x = X + (size_t)row * 512;
  const float* y = Y + (size_t)row * 512;
  float v0 = x[t] + y[t];
  float v1 = x[t + 256] + y[t + 256];
  float s = v0 + v1, ss = v0 * v0 + v1 * v1;
#pragma unroll
  for (int m = 1; m < 64; m <<= 1) { s += __shfl_xor(s, m); ss += __shfl_xor(ss, m); }
  __shared__ float red[2][4];
  int wid = t >> 6;
  if ((t & 63) == 0) { red[0][wid] = s; red[1][wid] = ss; }
  __syncthreads();
  s = red[0][0] + red[0][1] + red[0][2] + red[0][3];
  ss = red[1][0] + red[1][1] + red[1][2] + red[1][3];
  float mean = s * (1.f / 512.f);
  float var = ss * (1.f / 512.f) - mean * mean;
  float rstd = rsqrtf(var + 1e-10f);
  float o0 = gam[t] * (v0 - mean) * rstd + bet[t];
  float o1 = gam[t + 256] * (v1 - mean) * rstd + bet[t + 256];
  float* of = outf + (size_t)row * 512;
  of[t] = o0;
  of[t + 256] = o1;
  if (outb) {
    u16* ob = outb + (size_t)row * 512;
    ob[t] = f2bf(o0);
    ob[t + 256] = f2bf(o1);
  }
}

extern "C" void kernel_launch(void* const* d_in, const int* in_sizes, int n_in,
                              void* d_out, int out_size, void* d_ws, size_t ws_size,
                              hipStream_t stream) {
  const float* x  = (const float*)d_in[0];
  const float* Wq = (const float*)d_in[1];
  const float* bq = (const float*)d_in[2];
  const float* Wk = (const float*)d_in[3];
  const float* bk = (const float*)d_in[4];
  const float* Wv = (const float*)d_in[5];
  const float* bv = (const float*)d_in[6];
  const float* Wo = (const float*)d_in[7];
  const float* bo = (const float*)d_in[8];
  const float* W1 = (const float*)d_in[9];
  const float* b1 = (const float*)d_in[10];
  const float* W2 = (const float*)d_in[11];
  const float* b2 = (const float*)d_in[12];
  const float* g1 = (const float*)d_in[13];
  const float* be1 = (const float*)d_in[14];
  const float* g2 = (const float*)d_in[15];
  const float* be2 = (const float*)d_in[16];
  // d_in[17] = mask: exactly causal, applied analytically.

  char* ws = (char*)d_ws;
  // region 0 [0,8M): xb -> att -> h1b (sequential lifetimes)
  u16* xb   = (u16*)(ws + 0);
  u16* attb = (u16*)(ws + 0);
  u16* h1b  = (u16*)(ws + 0);
  // region 1 [8M,~14.7M): bf16 transposed weights + packed bias (persistent)
  u16* WqkvT = (u16*)(ws + (size_t)(8u << 20));
  u16* WoT = WqkvT + 786432;
  u16* W1T = WoT + 262144;
  u16* W2T = W1T + 1048576;
  float* bqkv = (float*)(W2T + 1048576);
  // region 2 [16M,49.6M): QKV -> attproj -> ff1 (sequential lifetimes)
  u16* QKV = (u16*)(ws + (size_t)(16u << 20));
  float* attproj = (float*)(ws + (size_t)(16u << 20));
  u16* ff1 = (u16*)(ws + (size_t)(16u << 20));
  // region 3 [50M,66.8M): ffn2
  float* ffn2 = (float*)(ws + (size_t)(50u << 20));
  // h1 (fp32) parked in d_out, overwritten by final LN
  float* h1f = (float*)d_out;

  // 1) converts / transposes
  k_cvt<<<2048, 256, 0, stream>>>((const float4*)x, (uint4*)xb, 524288);
  k_transpose_qkv<<<dim3(1, 16, 24), 256, 0, stream>>>(Wq, Wk, Wv, WqkvT);
  k_transpose<<<dim3(8, 16, 1), 256, 0, stream>>>(Wo, WoT, 512, 512);
  k_transpose<<<dim3(32, 16, 1), 256, 0, stream>>>(W1, W1T, 512, 2048);
  k_transpose<<<dim3(8, 64, 1), 256, 0, stream>>>(W2, W2T, 2048, 512);
  k_pack_bias<<<6, 256, 0, stream>>>(bq, bk, bv, bqkv);

  // 2) QKV projection: (8192,512) @ (512,1536)
  k_gemm<0, 128><<<dim3(64, 12), 256, 0, stream>>>(xb, WqkvT, bqkv, QKV, 8192, 1536, 512);
  // 3) causal attention (1024 balanced blocks, XCD-local)
  k_attn<<<1024, 256, 0, stream>>>(QKV, attb);
  // 4) output projection (fp32 out), BN=64 for 2 blocks/CU
  k_gemm<2, 64><<<dim3(64, 8), 256, 0, stream>>>(attb, WoT, bo, attproj, 8192, 512, 512);
  // 5) h1 = LN(x + attproj)
  k_add_ln<<<8192, 256, 0, stream>>>(x, attproj, g1, be1, h1f, h1b);
  // 6) FFN
  k_gemm<1, 128><<<dim3(64, 16), 256, 0, stream>>>(h1b, W1T, b1, ff1, 8192, 2048, 512);
  k_gemm<2, 64><<<dim3(64, 8), 256, 0, stream>>>(ff1, W2T, b2, ffn2, 8192, 512, 2048);
  // 7) out = LN(h1 + ffn2)
  k_add_ln<<<8192, 256, 0, stream>>>(h1f, ffn2, g2, be2, (float*)d_out, nullptr);
}

// Round 5
// 201.344 us; speedup vs baseline: 1.4606x; 1.0828x over previous
//
#include <hip/hip_runtime.h>
#include <cstdint>

typedef unsigned short u16;
typedef __bf16 bf16x8 __attribute__((ext_vector_type(8)));
typedef float f32x4 __attribute__((ext_vector_type(4)));
struct __align__(8) U2 { unsigned x, y; };

#define NEG_INF (-__builtin_inff())

__device__ __forceinline__ u16 f2bf(float f) {
  unsigned u = __builtin_bit_cast(unsigned, f);
  u += 0x7FFFu + ((u >> 16) & 1u);
  return (u16)(u >> 16);
}
__device__ __forceinline__ u16 bfbits(__bf16 x) { return __builtin_bit_cast(u16, x); }
__device__ __forceinline__ unsigned pk2(float a, float b) {
  u16 lo = bfbits((__bf16)a), hi = bfbits((__bf16)b);
  return (unsigned)lo | ((unsigned)hi << 16);
}

// global->LDS async copy, 16B per lane. LDS dest is wave-uniform base + lane*16.
__device__ __forceinline__ void async16(u16* dst, const u16* src) {
  __builtin_amdgcn_global_load_lds(
      (__attribute__((address_space(1))) void*)(u16*)src,
      (__attribute__((address_space(3))) void*)dst, 16, 0, 0);
}

// ---------------- fp32 -> bf16 convert (8 elems/thread) ----------------
__global__ __launch_bounds__(256) void k_cvt(const float4* __restrict__ in,
                                             uint4* __restrict__ out, int n8) {
  int i = blockIdx.x * 256 + threadIdx.x;
  if (i >= n8) return;
  float4 a = in[2 * i], b = in[2 * i + 1];
  uint4 r;
  r.x = (unsigned)f2bf(a.x) | ((unsigned)f2bf(a.y) << 16);
  r.y = (unsigned)f2bf(a.z) | ((unsigned)f2bf(a.w) << 16);
  r.z = (unsigned)f2bf(b.x) | ((unsigned)f2bf(b.y) << 16);
  r.w = (unsigned)f2bf(b.z) | ((unsigned)f2bf(b.w) << 16);
  out[i] = r;
}

// ------------- batched transpose+convert: in (B,R,C) f32 -> out (B,C,R) bf16 -------------
__global__ __launch_bounds__(256) void k_transpose(const float* __restrict__ in,
                                                   u16* __restrict__ out, int R, int C) {
  __shared__ float t[32][65];
  int b = blockIdx.z;
  int r0 = blockIdx.y * 32, c0 = blockIdx.x * 64;
  const float* ip = in + (size_t)b * R * C;
  u16* op = out + (size_t)b * R * C;
  int tx = threadIdx.x & 63, ty = threadIdx.x >> 6;
#pragma unroll
  for (int i = 0; i < 32; i += 4) {
    int r = r0 + ty + i, c = c0 + tx;
    t[ty + i][tx] = (r < R && c < C) ? ip[(size_t)r * C + c] : 0.f;
  }
  __syncthreads();
  int cx = threadIdx.x & 31, cy = threadIdx.x >> 5;
#pragma unroll
  for (int j = 0; j < 64; j += 8) {
    int oc = c0 + cy + j, orr = r0 + cx;
    if (oc < C && orr < R) op[(size_t)oc * R + orr] = f2bf(t[cx][cy + j]);
  }
}

// merged Wq/Wk/Wv transpose: 24 batches of (512,64) -> (64,512)
__global__ __launch_bounds__(256) void k_transpose_qkv(const float* __restrict__ Wq,
                                                       const float* __restrict__ Wk,
                                                       const float* __restrict__ Wv,
                                                       u16* __restrict__ out) {
  __shared__ float t[32][65];
  int z = blockIdx.z;
  const float* W = (z < 8) ? Wq : (z < 16) ? Wk : Wv;
  const float* ip = W + (size_t)(z & 7) * 32768;
  u16* op = out + (size_t)z * 32768;
  int r0 = blockIdx.y * 32;
  int tx = threadIdx.x & 63, ty = threadIdx.x >> 6;
#pragma unroll
  for (int i = 0; i < 32; i += 4)
    t[ty + i][tx] = ip[(size_t)(r0 + ty + i) * 64 + tx];
  __syncthreads();
  int cx = threadIdx.x & 31, cy = threadIdx.x >> 5;
#pragma unroll
  for (int j = 0; j < 64; j += 8)
    op[(size_t)(cy + j) * 512 + r0 + cx] = f2bf(t[cx][cy + j]);
}

__global__ __launch_bounds__(256) void k_pack_bias(const float* __restrict__ bq,
                                                   const float* __restrict__ bk,
                                                   const float* __restrict__ bv,
                                                   float* __restrict__ bpk) {
  int i = blockIdx.x * 256 + threadIdx.x;
  if (i < 1536) {
    int m = i >> 9, r = i & 511;
    const float* B = (m == 0) ? bq : (m == 1) ? bk : bv;
    bpk[i] = B[r];
  }
}

// ---------------- bf16 MFMA GEMM: C(M,N) = A(M,K) * BT(N,K)^T + bias ----------------
// EPI: 0 = bf16 store, 1 = bf16 store + relu, 2 = f32 store
// BN: 128 (wave tile 64x64) or 64 (wave tile 64x32, 2x blocks for small N)
template <int EPI, int BN>
__global__ __launch_bounds__(256) void k_gemm(const u16* __restrict__ A,
                                              const u16* __restrict__ BT,
                                              const float* __restrict__ bias,
                                              void* __restrict__ Cout,
                                              int M, int N, int Kd) {
  __shared__ __align__(16) u16 lds[8192 + BN * 64];  // A [128][64] + B [BN][64], XOR-swizzled
  constexpr int NFR = BN / 32;    // N frags per wave
  constexpr int BITER = BN / 32;  // B staging iters per wave
  const int tid = threadIdx.x, wid = tid >> 6, lane = tid & 63;
  const int lr = lane & 15, lg = lane >> 4;
  const int wr = wid >> 1, wc = wid & 1;
  const int tm = blockIdx.x * 128, tn = blockIdx.y * BN;
  const char* lp = (const char*)lds;

  f32x4 acc[4][NFR] = {};

  const int srow = lane >> 3;            // row within 8-row staging region
  const int kb = (lane & 7) ^ srow;      // pre-swizzled source chunk

  for (int kt = 0; kt < Kd; kt += 64) {
#pragma unroll
    for (int it = 0; it < 4; ++it) {
      int rid = wid * 4 + it;
      int row = rid * 8 + srow;
      async16(&lds[rid * 512], A + (size_t)(tm + row) * Kd + kt + kb * 8);
    }
#pragma unroll
    for (int it = 0; it < BITER; ++it) {
      int rid = wid * BITER + it;
      int row = rid * 8 + srow;
      async16(&lds[8192 + rid * 512], BT + (size_t)(tn + row) * Kd + kt + kb * 8);
    }
    __syncthreads();
#pragma unroll
    for (int ks = 0; ks < 2; ++ks) {
      const int kbyte = ks * 64 + lg * 16;
      bf16x8 af[4], bfr[NFR];
#pragma unroll
      for (int mi = 0; mi < 4; ++mi) {
        int row = wr * 64 + mi * 16 + lr;
        af[mi] = *(const bf16x8*)(lp + row * 128 + (kbyte ^ ((row & 7) << 4)));
      }
#pragma unroll
      for (int nj = 0; nj < NFR; ++nj) {
        int row = wc * (BN / 2) + nj * 16 + lr;
        bfr[nj] = *(const bf16x8*)(lp + 16384 + row * 128 + (kbyte ^ ((row & 7) << 4)));
      }
#pragma unroll
      for (int mi = 0; mi < 4; ++mi)
#pragma unroll
        for (int nj = 0; nj < NFR; ++nj)
          acc[mi][nj] = __builtin_amdgcn_mfma_f32_16x16x32_bf16(af[mi], bfr[nj], acc[mi][nj], 0, 0, 0);
    }
    __syncthreads();
  }

#pragma unroll
  for (int mi = 0; mi < 4; ++mi)
#pragma unroll
    for (int nj = 0; nj < NFR; ++nj) {
      int col = tn + wc * (BN / 2) + nj * 16 + lr;
      float bv = bias[col];
#pragma unroll
      for (int r = 0; r < 4; ++r) {
        int row = tm + wr * 64 + mi * 16 + lg * 4 + r;
        float v = acc[mi][nj][r] + bv;
        if (EPI == 1) v = v > 0.f ? v : 0.f;
        if (EPI == 2)
          ((float*)Cout)[(size_t)row * N + col] = v;
        else
          ((u16*)Cout)[(size_t)row * N + col] = f2bf(v);
      }
    }
}

// ---------------- causal flash attention ----------------
// 512 balanced paired blocks (p, 31-p), swapped QK^T AND swapped PV so the
// q index is lane-local (col=lr) in BOTH S and O: no cross-lane broadcasts.
// Per-tile cross-lane ops: 2 shfl (row max) only. T13 defer-max skips rescale.
// QKV: (8192, 1536) bf16, cols [q | k | v] each h*64+e. att out: (8192, 512) bf16.
__global__ __launch_bounds__(256) void k_attn(const u16* __restrict__ QKV,
                                              u16* __restrict__ att) {
  // LDS bytes: K dbuf [0,16K) | V^T dbuf [16K,32K) | P 4x[16][64] [32K,40K)
  __shared__ __align__(16) u16 lds[20480];
  // XCD-bijective remap: 512 blocks = 8 XCD x 64; all 16 p of 4 heads per XCD.
  const int lin = blockIdx.x;
  const int L = (lin & 7) * 64 + (lin >> 3);
  const int p = L & 15, nh = L >> 4;
  const int n = nh >> 3, h = nh & 7;
  const int tid = threadIdx.x, wid = tid >> 6, lane = tid & 63;
  const int lr = lane & 15, lg = lane >> 4;
  char* lp = (char*)lds;
  const u16* Qp = QKV + (size_t)(n * 2048) * 1536 + h * 64;
  const u16* Kp = Qp + 512;
  const u16* Vp = Qp + 1024;

  const int vkv = (tid & 31) * 2;   // V staging: kv pair base
  const int vd0 = (tid >> 5) * 8;   // V staging: d chunk
  const int pwb = 32768 + wid * 2048;  // byte base of this wave's P
  const float C2 = 0.18033688011112042f;  // log2(e)/8

  for (int ph = 0; ph < 2; ++ph) {
    const int qc = (ph == 0) ? p : 31 - p;
    const int ntiles = qc + 1;
    const int qw = qc * 64 + wid * 16;
    const int qa = qw + lr;  // this lane's q row (sequence-local)

    bf16x8 qf[2];
#pragma unroll
    for (int ks = 0; ks < 2; ++ks)
      qf[ks] = *(const bf16x8*)(Qp + (size_t)(qw + lr) * 1536 + ks * 32 + lg * 8);

    f32x4 o[4] = {};          // o[nd]: D[d=nd*16+lg*4+r][q=lr]
    float mstat = NEG_INF, lpart = 0.f;
    int cur = 0;

    // prologue: stage tile 0 into buffer 0
#pragma unroll
    for (int it = 0; it < 2; ++it) {
      int c = (wid * 2 + it) * 64 + lane;
      int row = c >> 3, ce = ((c & 7) ^ (row & 7)) * 8;
      async16(&lds[(wid * 2 + it) * 512], Kp + (size_t)row * 1536 + ce);
    }
    {
      bf16x8 v0 = *(const bf16x8*)(Vp + (size_t)vkv * 1536 + vd0);
      bf16x8 v1 = *(const bf16x8*)(Vp + (size_t)(vkv + 1) * 1536 + vd0);
#pragma unroll
      for (int jj = 0; jj < 8; ++jj) {
        int d = vd0 + jj;
        unsigned pk = (unsigned)bfbits(v0[jj]) | ((unsigned)bfbits(v1[jj]) << 16);
        *(unsigned*)(lp + 16384 + d * 128 + ((vkv * 2) ^ ((d & 7) << 4))) = pk;
      }
    }
    __syncthreads();

    for (int t = 0; t < ntiles; ++t) {
      const int nxt = cur ^ 1;
      bf16x8 va, vb;
      const bool pre = (t + 1 < ntiles);
      if (pre) {
        const int kvn = (t + 1) * 64;
        // issue K(t+1) -> LDS[alt] and V(t+1) -> regs; latency hides under compute
#pragma unroll
        for (int it = 0; it < 2; ++it) {
          int c = (wid * 2 + it) * 64 + lane;
          int row = c >> 3, ce = ((c & 7) ^ (row & 7)) * 8;
          async16(&lds[nxt * 4096 + (wid * 2 + it) * 512],
                  Kp + (size_t)(kvn + row) * 1536 + ce);
        }
        va = *(const bf16x8*)(Vp + (size_t)(kvn + vkv) * 1536 + vd0);
        vb = *(const bf16x8*)(Vp + (size_t)(kvn + vkv + 1) * 1536 + vd0);
      }

      // S^T = K Q^T : lane holds q=lr, kv = nj*16+lg*4+r
      const int kv0 = t * 64;
      f32x4 s[4] = {};
#pragma unroll
      for (int nj = 0; nj < 4; ++nj) {
        int row = nj * 16 + lr;
#pragma unroll
        for (int ks = 0; ks < 2; ++ks) {
          bf16x8 kf = *(const bf16x8*)(lp + cur * 8192 + row * 128 +
                                       ((ks * 64 + lg * 16) ^ ((row & 7) << 4)));
          s[nj] = __builtin_amdgcn_mfma_f32_16x16x32_bf16(kf, qf[ks], s[nj], 0, 0, 0);
        }
      }

      // causal mask: diagonal tile is always the last one of this chunk
      if (t == ntiles - 1) {
#pragma unroll
        for (int nj = 0; nj < 4; ++nj) {
          int kvb = kv0 + nj * 16 + lg * 4;
#pragma unroll
          for (int r = 0; r < 4; ++r)
            if (kvb + r > qa) s[nj][r] = NEG_INF;
        }
      }

      // row max for q=lr: in-lane over 16, then across the 4 kv-lanes
      float mx = s[0][0];
#pragma unroll
      for (int nj = 0; nj < 4; ++nj)
#pragma unroll
        for (int r = 0; r < 4; ++r) mx = fmaxf(mx, s[nj][r]);
      mx = fmaxf(mx, __shfl_xor(mx, 16));
      mx = fmaxf(mx, __shfl_xor(mx, 32));

      // T13 defer-max: only rescale when max grew > 8 exp2-units (P <= 2^8)
      if (__any(mx > mstat + 44.361419556f)) {
        float mnew = fmaxf(mstat, mx);
        float corr = exp2f((mstat - mnew) * C2);
        lpart *= corr;
#pragma unroll
        for (int nd = 0; nd < 4; ++nd)
#pragma unroll
          for (int r = 0; r < 4; ++r) o[nd][r] *= corr;
        mstat = mnew;
      }

      // P = exp2((s - m) * C2); per-lane partial sum only (reduce at end)
      float psum = 0.f;
#pragma unroll
      for (int nj = 0; nj < 4; ++nj)
#pragma unroll
        for (int r = 0; r < 4; ++r) {
          float pv = exp2f((s[nj][r] - mstat) * C2);
          s[nj][r] = pv;
          psum += pv;
        }
      lpart += psum;

      // write P[q=lr][kv] (wave-private, swizzled): 4 consecutive kv packed -> b64
#pragma unroll
      for (int nj = 0; nj < 4; ++nj) {
        U2 val;
        val.x = pk2(s[nj][0], s[nj][1]);
        val.y = pk2(s[nj][2], s[nj][3]);
        *(U2*)(lp + pwb + lr * 128 + ((nj * 32 + lg * 8) ^ ((lr & 7) << 4))) = val;
      }

      // PV swapped: o = mfma(A=V^T[d][kv], B=P[q][kv]) -> D[d][q], col q = lr
      bf16x8 pa[2];
#pragma unroll
      for (int ks = 0; ks < 2; ++ks)
        pa[ks] = *(const bf16x8*)(lp + pwb + lr * 128 +
                                  ((ks * 64 + lg * 16) ^ ((lr & 7) << 4)));
#pragma unroll
      for (int nd = 0; nd < 4; ++nd) {
        int row = nd * 16 + lr;
#pragma unroll
        for (int ks = 0; ks < 2; ++ks) {
          bf16x8 vf = *(const bf16x8*)(lp + 16384 + cur * 8192 + row * 128 +
                                       ((ks * 64 + lg * 16) ^ ((row & 7) << 4)));
          o[nd] = __builtin_amdgcn_mfma_f32_16x16x32_bf16(vf, pa[ks], o[nd], 0, 0, 0);
        }
      }

      // land V(t+1) into LDS[alt] after compute (global latency already covered)
      if (pre) {
#pragma unroll
        for (int jj = 0; jj < 8; ++jj) {
          int d = vd0 + jj;
          unsigned pk = (unsigned)bfbits(va[jj]) | ((unsigned)bfbits(vb[jj]) << 16);
          *(unsigned*)(lp + 16384 + nxt * 8192 + d * 128 + ((vkv * 2) ^ ((d & 7) << 4))) = pk;
        }
      }
      __syncthreads();  // drains vmcnt (K async) + lgkm before next tile
      cur = nxt;
    }

    // deferred l reduction (once per phase), all lane-local after 2 shfls
    float lsum = lpart;
    lsum += __shfl_xor(lsum, 16);
    lsum += __shfl_xor(lsum, 32);
    float li = 1.0f / lsum;

    // epilogue: lane's q = lr; d = nd*16 + lg*4 + r -> 4 U2 stores of 4 bf16
    u16* ap = att + (size_t)(n * 2048 + qw + lr) * 512 + h * 64 + lg * 4;
#pragma unroll
    for (int nd = 0; nd < 4; ++nd) {
      U2 val;
      val.x = pk2(o[nd][0] * li, o[nd][1] * li);
      val.y = pk2(o[nd][2] * li, o[nd][3] * li);
      *(U2*)(ap + nd * 16) = val;
    }
  }
}

// ---------------- residual add + LayerNorm (D=512), optional bf16 copy ----------------
__global__ __launch_bounds__(256) void k_add_ln(const float* __restrict__ X,
                                                const float* __restrict__ Y,
                                                const float* __restrict__ gam,
                                                const float* __restrict__ bet,
                                                float* __restrict__ outf,
                                                u16* __restrict__ outb) {
  int row = blockIdx.x, t = threadIdx.x;
  const float* x = X + (size_t)row * 512;
  const float* y = Y + (size_t)row * 512;
  float v0 = x[t] + y[t];
  float v1 = x[t + 256] + y[t + 256];
  float s = v0 + v1, ss = v0 * v0 + v1 * v1;
#pragma unroll
  for (int m = 1; m < 64; m <<= 1) { s += __shfl_xor(s, m); ss += __shfl_xor(ss, m); }
  __shared__ float red[2][4];
  int wid = t >> 6;
  if ((t & 63) == 0) { red[0][wid] = s; red[1][wid] = ss; }
  __syncthreads();
  s = red[0][0] + red[0][1] + red[0][2] + red[0][3];
  ss = red[1][0] + red[1][1] + red[1][2] + red[1][3];
  float mean = s * (1.f / 512.f);
  float var = ss * (1.f / 512.f) - mean * mean;
  float rstd = rsqrtf(var + 1e-10f);
  float o0 = gam[t] * (v0 - mean) * rstd + bet[t];
  float o1 = gam[t + 256] * (v1 - mean) * rstd + bet[t + 256];
  float* of = outf + (size_t)row * 512;
  of[t] = o0;
  of[t + 256] = o1;
  if (outb) {
    u16* ob = outb + (size_t)row * 512;
    ob[t] = f2bf(o0);
    ob[t + 256] = f2bf(o1);
  }
}

extern "C" void kernel_launch(void* const* d_in, const int* in_sizes, int n_in,
                              void* d_out, int out_size, void* d_ws, size_t ws_size,
                              hipStream_t stream) {
  const float* x  = (const float*)d_in[0];
  const float* Wq = (const float*)d_in[1];
  const float* bq = (const float*)d_in[2];
  const float* Wk = (const float*)d_in[3];
  const float* bk = (const float*)d_in[4];
  const float* Wv = (const float*)d_in[5];
  const float* bv = (const float*)d_in[6];
  const float* Wo = (const float*)d_in[7];
  const float* bo = (const float*)d_in[8];
  const float* W1 = (const float*)d_in[9];
  const float* b1 = (const float*)d_in[10];
  const float* W2 = (const float*)d_in[11];
  const float* b2 = (const float*)d_in[12];
  const float* g1 = (const float*)d_in[13];
  const float* be1 = (const float*)d_in[14];
  const float* g2 = (const float*)d_in[15];
  const float* be2 = (const float*)d_in[16];
  // d_in[17] = mask: exactly causal, applied analytically.

  char* ws = (char*)d_ws;
  // region 0 [0,8M): xb -> att -> h1b (sequential lifetimes)
  u16* xb   = (u16*)(ws + 0);
  u16* attb = (u16*)(ws + 0);
  u16* h1b  = (u16*)(ws + 0);
  // region 1 [8M,~14.7M): bf16 transposed weights + packed bias (persistent)
  u16* WqkvT = (u16*)(ws + (size_t)(8u << 20));
  u16* WoT = WqkvT + 786432;
  u16* W1T = WoT + 262144;
  u16* W2T = W1T + 1048576;
  float* bqkv = (float*)(W2T + 1048576);
  // region 2 [16M,49.6M): QKV -> attproj -> ff1 (sequential lifetimes)
  u16* QKV = (u16*)(ws + (size_t)(16u << 20));
  float* attproj = (float*)(ws + (size_t)(16u << 20));
  u16* ff1 = (u16*)(ws + (size_t)(16u << 20));
  // region 3 [50M,66.8M): ffn2
  float* ffn2 = (float*)(ws + (size_t)(50u << 20));
  // h1 (fp32) parked in d_out, overwritten by final LN
  float* h1f = (float*)d_out;

  // 1) converts / transposes
  k_cvt<<<2048, 256, 0, stream>>>((const float4*)x, (uint4*)xb, 524288);
  k_transpose_qkv<<<dim3(1, 16, 24), 256, 0, stream>>>(Wq, Wk, Wv, WqkvT);
  k_transpose<<<dim3(8, 16, 1), 256, 0, stream>>>(Wo, WoT, 512, 512);
  k_transpose<<<dim3(32, 16, 1), 256, 0, stream>>>(W1, W1T, 512, 2048);
  k_transpose<<<dim3(8, 64, 1), 256, 0, stream>>>(W2, W2T, 2048, 512);
  k_pack_bias<<<6, 256, 0, stream>>>(bq, bk, bv, bqkv);

  // 2) QKV projection: (8192,512) @ (512,1536)
  k_gemm<0, 128><<<dim3(64, 12), 256, 0, stream>>>(xb, WqkvT, bqkv, QKV, 8192, 1536, 512);
  // 3) causal attention (512 balanced paired blocks, XCD-local)
  k_attn<<<512, 256, 0, stream>>>(QKV, attb);
  // 4) output projection (fp32 out), BN=64 for 2 blocks/CU
  k_gemm<2, 64><<<dim3(64, 8), 256, 0, stream>>>(attb, WoT, bo, attproj, 8192, 512, 512);
  // 5) h1 = LN(x + attproj)
  k_add_ln<<<8192, 256, 0, stream>>>(x, attproj, g1, be1, h1f, h1b);
  // 6) FFN
  k_gemm<1, 128><<<dim3(64, 16), 256, 0, stream>>>(h1b, W1T, b1, ff1, 8192, 2048, 512);
  k_gemm<2, 64><<<dim3(64, 8), 256, 0, stream>>>(ff1, W2T, b2, ffn2, 8192, 512, 2048);
  // 7) out = LN(h1 + ffn2)
  k_add_ln<<<8192, 256, 0, stream>>>(h1f, ffn2, g2, be2, (float*)d_out, nullptr);
}